// Round 3
// baseline (6000.848 us; speedup 1.0000x reference)
//
#include <hip/hip_runtime.h>
#include <cmath>

// ---------------------------------------------------------------------------
// MutualTimeSformer — round 6: GEMMs were staging-BW-bound (64 FLOP/B @ 5TB/s
// = 320 TF observed). Fix: 256-row tiles (85-128 FLOP/B), 512-thread blocks,
// XCD-bijective block remap for L2-local A panels. MP = 4864 = 19*256.
// ---------------------------------------------------------------------------

#define NT      4801
#define NP      4800
#define MP      4864          // padded row count (19 * 256)
#define DM      512
#define QKV_ST  1536
#define LN_EPS  1e-5f
#define NCH     49            // cls split-K chunks (49*100 >= 4801)

typedef __attribute__((ext_vector_type(8))) short bf16x8;
typedef __attribute__((ext_vector_type(4))) float f32x4;

__device__ __forceinline__ unsigned short f2b(float f) {
    union { float f; unsigned int u; } x; x.f = f;
    unsigned int r = (x.u + 0x7FFFu + ((x.u >> 16) & 1u)) >> 16;
    return (unsigned short)r;
}
__device__ __forceinline__ float b2f(unsigned short b) {
    union { unsigned int u; float f; } x; x.u = ((unsigned int)b) << 16;
    return x.f;
}
__device__ __forceinline__ unsigned int pack2(float a, float b) {
    return (unsigned int)f2b(a) | ((unsigned int)f2b(b) << 16);
}

__device__ __forceinline__ void gl_lds16(const void* g, void* l) {
    __builtin_amdgcn_global_load_lds(
        (__attribute__((address_space(1))) unsigned int*)(unsigned long long)(uintptr_t)g,
        (__attribute__((address_space(3))) unsigned int*)l, 16, 0, 0);
}

// bijective XCD-chunk remap (m204): launch-id round-robins XCDs; remap so each
// XCD owns a contiguous chunk of logical tiles (consecutive = same A row-panel).
__device__ __forceinline__ void xcd_remap(int& bx, int& by, int& bz) {
    const int gx = gridDim.x, gy = gridDim.y;
    const int nwg = gx * gy * gridDim.z;
    const int orig = (blockIdx.z * gy + blockIdx.y) * gx + blockIdx.x;
    const int q = nwg >> 3, r = nwg & 7;
    const int xcd = orig & 7, idx = orig >> 3;
    const int id = (xcd < r ? xcd * (q + 1) : r * (q + 1) + (xcd - r) * q) + idx;
    bx = id % gx;
    const int t = id / gx;
    by = t % gy;
    bz = t / gy;
}

// ------------------------------ patchify (fp32 -> bf16) --------------------
__global__ void patchify_kernel(const float* __restrict__ video, unsigned short* __restrict__ out)
{
    int idx = blockIdx.x * 256 + threadIdx.x;
    if (idx >= NP * 768) return;
    int tok = idx / 768, e = idx % 768;
    int c  = e % 3;
    int pe = e / 3;
    int p2 = pe % 16, p1 = pe / 16;
    int half = tok / 2400, r = tok % 2400;
    int f = r / 600, rr = r % 600;
    int hi = rr / 20, wi = rr % 20;
    int row = hi * 16 + p1;
    int col = half * 320 + wi * 16 + p2;
    out[idx] = f2b(video[(((size_t)f * 3 + c) * 480 + row) * 640 + col]);
}

__global__ void cls_init_kernel(const float* __restrict__ cls_token,
                                const float* __restrict__ pos, float* __restrict__ X)
{
    int d = blockIdx.x * 256 + threadIdx.x;
    if (d < DM) X[d] = cls_token[d] + pos[d];
}

// pre-init X rows 1..4800 with pos_emb (patch GEMM atomically accumulates)
__global__ void posx_init(const float* __restrict__ pos, float* __restrict__ X)
{
    int i = blockIdx.x * 256 + threadIdx.x;
    if (i < NP * DM / 4)
        ((float4*)(X + DM))[i] = ((const float4*)(pos + DM))[i];
}

// ------------------------------ weight transpose-convert -------------------
__device__ __forceinline__ void transpose_tile(const float* __restrict__ in,
                                               unsigned short* __restrict__ out,
                                               int K, int N, int tile)
{
    __shared__ float T[32][33];
    int ntk = K / 32;
    int kt = tile % ntk, nt = tile / ntk;
    int k0 = kt * 32, n0 = nt * 32;
    int tx = threadIdx.x & 31, ty = threadIdx.x >> 5;
    #pragma unroll
    for (int i = 0; i < 4; i++)
        T[ty + 8 * i][tx] = in[(size_t)(k0 + ty + 8 * i) * N + n0 + tx];
    __syncthreads();
    #pragma unroll
    for (int i = 0; i < 4; i++)
        out[(size_t)(n0 + ty + 8 * i) * K + k0 + tx] = f2b(T[tx][ty + 8 * i]);
}

__global__ __launch_bounds__(256) void convertT_layer(
    const float* __restrict__ w0, const float* __restrict__ w1,
    const float* __restrict__ w2, const float* __restrict__ w3,
    const float* __restrict__ w4, const float* __restrict__ w5,
    unsigned short* __restrict__ out)
{
    int t = blockIdx.x;
    if      (t <  768) transpose_tile(w0, out + 0,       512, 1536, t);
    else if (t < 1024) transpose_tile(w1, out + 786432,  512,  512, t - 768);
    else if (t < 1792) transpose_tile(w2, out + 1048576, 512, 1536, t - 1024);
    else if (t < 2048) transpose_tile(w3, out + 1835008, 512,  512, t - 1792);
    else if (t < 4096) transpose_tile(w4, out + 2097152, 512, 4096, t - 2048);
    else               transpose_tile(w5, out + 4194304, 2048, 512, t - 4096);
}

__global__ __launch_bounds__(256) void convertT_one(
    const float* __restrict__ in, unsigned short* __restrict__ out, int K, int N)
{
    transpose_tile(in, out, K, N, blockIdx.x);
}

// ------------------------------ MFMA GEMM (BM=256, 512 thr, dbuf) ----------
// 8 waves in 4x2; wave tile 64 x (BN/2). A chunks/thread=4, B chunks=BN/64.
template<int BN, bool OB16>
__global__ __launch_bounds__(512, 2) void mfma_gemm(
    const unsigned short* __restrict__ A, const unsigned short* __restrict__ BT,
    const float* __restrict__ bias, const float* __restrict__ add,
    void* __restrict__ C, int Mv, int N, int K)
{
    constexpr int NB = BN / 64;      // B stage chunks per thread
    constexpr int NF = BN / 32;      // N-fragments per wave
    __shared__ short Asm[2][256 * 64];
    __shared__ short Bsm[2][BN * 64];
    int bx, by, bz; xcd_remap(bx, by, bz); (void)bz;
    const int tid = threadIdx.x, w = tid >> 6, lane = tid & 63;
    const int row0 = by * 256, col0 = bx * BN;
    const int wm = w >> 1, wn = w & 1;
    const int l15 = lane & 15, quad = lane >> 4;

    f32x4 acc[4][NF] = {};

    int ar[4], aq[4];
    #pragma unroll
    for (int i = 0; i < 4; i++) {
        int c = (w * 4 + i) * 64 + lane;
        ar[i] = c >> 3;
        aq[i] = (c & 7) ^ ((c >> 3) & 7);
    }
    int br[NB], bq[NB];
    #pragma unroll
    for (int i = 0; i < NB; i++) {
        int c = (w * NB + i) * 64 + lane;
        br[i] = c >> 3;
        bq[i] = (c & 7) ^ ((c >> 3) & 7);
    }
    const unsigned short* Ab = A  + (size_t)row0 * K;
    const unsigned short* Bb = BT + (size_t)col0 * K;

    // prologue: stage k-tile 0 into buffer 0
    #pragma unroll
    for (int i = 0; i < 4; i++)
        gl_lds16(Ab + (size_t)ar[i] * K + aq[i] * 8, &Asm[0][(w * 4 + i) * 512]);
    #pragma unroll
    for (int i = 0; i < NB; i++)
        gl_lds16(Bb + (size_t)br[i] * K + bq[i] * 8, &Bsm[0][(w * NB + i) * 512]);
    asm volatile("s_waitcnt vmcnt(0)" ::: "memory");
    __builtin_amdgcn_s_barrier();

    const int nt = K >> 6;
    int cur = 0;
    for (int t = 0; t < nt; t++) {
        if (t + 1 < nt) {
            const int k0 = (t + 1) << 6;
            #pragma unroll
            for (int i = 0; i < 4; i++)
                gl_lds16(Ab + (size_t)ar[i] * K + k0 + aq[i] * 8,
                         &Asm[cur ^ 1][(w * 4 + i) * 512]);
            #pragma unroll
            for (int i = 0; i < NB; i++)
                gl_lds16(Bb + (size_t)br[i] * K + k0 + bq[i] * 8,
                         &Bsm[cur ^ 1][(w * NB + i) * 512]);
        }
        __builtin_amdgcn_sched_barrier(0);
        const short* As = Asm[cur];
        const short* Bs = Bsm[cur];
        #pragma unroll
        for (int ks = 0; ks < 2; ks++) {
            bf16x8 af[4], bfr[NF];
            #pragma unroll
            for (int i = 0; i < 4; i++) {
                int m = wm * 64 + i * 16 + l15;
                af[i] = *(const bf16x8*)&As[m * 64 + (((ks * 4 + quad) ^ (m & 7))) * 8];
            }
            #pragma unroll
            for (int j = 0; j < NF; j++) {
                int n = wn * (BN / 2) + j * 16 + l15;
                bfr[j] = *(const bf16x8*)&Bs[n * 64 + (((ks * 4 + quad) ^ (n & 7))) * 8];
            }
            #pragma unroll
            for (int i = 0; i < 4; i++)
                #pragma unroll
                for (int j = 0; j < NF; j++)
                    acc[i][j] = __builtin_amdgcn_mfma_f32_16x16x32_bf16(
                                    af[i], bfr[j], acc[i][j], 0, 0, 0);
        }
        asm volatile("s_waitcnt vmcnt(0)" ::: "memory");
        __builtin_amdgcn_s_barrier();
        cur ^= 1;
    }

    #pragma unroll
    for (int i = 0; i < 4; i++) {
        #pragma unroll
        for (int r = 0; r < 4; r++) {
            int row = row0 + wm * 64 + i * 16 + quad * 4 + r;
            if (row >= Mv) continue;
            #pragma unroll
            for (int j = 0; j < NF; j++) {
                int col = col0 + wn * (BN / 2) + j * 16 + l15;
                float v = acc[i][j][r];
                if (bias) v += bias[col];
                if (add)  v += add[(size_t)row * N + col];
                if (OB16) ((unsigned short*)C)[(size_t)row * N + col] = f2b(v);
                else      ((float*)C)[(size_t)row * N + col] = v;
            }
        }
    }
}

// ---------------- split-K MFMA GEMM (fp32 atomic accumulate into C) --------
// C pre-initialized with the additive term. bias added by kz==0 split only.
template<int BN, int SPLITS>
__global__ __launch_bounds__(512, 2) void mfma_gemm_sk(
    const unsigned short* __restrict__ A, const unsigned short* __restrict__ BT,
    const float* __restrict__ bias, float* __restrict__ C, int Mv, int N, int K)
{
    constexpr int NB = BN / 64;
    constexpr int NF = BN / 32;
    __shared__ short Asm[2][256 * 64];
    __shared__ short Bsm[2][BN * 64];
    int bx, by, bz; xcd_remap(bx, by, bz);
    const int tid = threadIdx.x, w = tid >> 6, lane = tid & 63;
    const int row0 = by * 256, col0 = bx * BN;
    const int wm = w >> 1, wn = w & 1;
    const int l15 = lane & 15, quad = lane >> 4;
    const int kchunk = K / SPLITS;
    const int kbeg = bz * kchunk;

    f32x4 acc[4][NF] = {};

    int ar[4], aq[4];
    #pragma unroll
    for (int i = 0; i < 4; i++) {
        int c = (w * 4 + i) * 64 + lane;
        ar[i] = c >> 3;
        aq[i] = (c & 7) ^ ((c >> 3) & 7);
    }
    int br[NB], bq[NB];
    #pragma unroll
    for (int i = 0; i < NB; i++) {
        int c = (w * NB + i) * 64 + lane;
        br[i] = c >> 3;
        bq[i] = (c & 7) ^ ((c >> 3) & 7);
    }
    const unsigned short* Ab = A  + (size_t)row0 * K + kbeg;
    const unsigned short* Bb = BT + (size_t)col0 * K + kbeg;

    #pragma unroll
    for (int i = 0; i < 4; i++)
        gl_lds16(Ab + (size_t)ar[i] * K + aq[i] * 8, &Asm[0][(w * 4 + i) * 512]);
    #pragma unroll
    for (int i = 0; i < NB; i++)
        gl_lds16(Bb + (size_t)br[i] * K + bq[i] * 8, &Bsm[0][(w * NB + i) * 512]);
    asm volatile("s_waitcnt vmcnt(0)" ::: "memory");
    __builtin_amdgcn_s_barrier();

    const int nt = kchunk >> 6;
    int cur = 0;
    for (int t = 0; t < nt; t++) {
        if (t + 1 < nt) {
            const int k0 = (t + 1) << 6;
            #pragma unroll
            for (int i = 0; i < 4; i++)
                gl_lds16(Ab + (size_t)ar[i] * K + k0 + aq[i] * 8,
                         &Asm[cur ^ 1][(w * 4 + i) * 512]);
            #pragma unroll
            for (int i = 0; i < NB; i++)
                gl_lds16(Bb + (size_t)br[i] * K + k0 + bq[i] * 8,
                         &Bsm[cur ^ 1][(w * NB + i) * 512]);
        }
        __builtin_amdgcn_sched_barrier(0);
        const short* As = Asm[cur];
        const short* Bs = Bsm[cur];
        #pragma unroll
        for (int ks = 0; ks < 2; ks++) {
            bf16x8 af[4], bfr[NF];
            #pragma unroll
            for (int i = 0; i < 4; i++) {
                int m = wm * 64 + i * 16 + l15;
                af[i] = *(const bf16x8*)&As[m * 64 + (((ks * 4 + quad) ^ (m & 7))) * 8];
            }
            #pragma unroll
            for (int j = 0; j < NF; j++) {
                int n = wn * (BN / 2) + j * 16 + l15;
                bfr[j] = *(const bf16x8*)&Bs[n * 64 + (((ks * 4 + quad) ^ (n & 7))) * 8];
            }
            #pragma unroll
            for (int i = 0; i < 4; i++)
                #pragma unroll
                for (int j = 0; j < NF; j++)
                    acc[i][j] = __builtin_amdgcn_mfma_f32_16x16x32_bf16(
                                    af[i], bfr[j], acc[i][j], 0, 0, 0);
        }
        asm volatile("s_waitcnt vmcnt(0)" ::: "memory");
        __builtin_amdgcn_s_barrier();
        cur ^= 1;
    }

    const bool addb = (bz == 0) && (bias != nullptr);
    #pragma unroll
    for (int i = 0; i < 4; i++) {
        #pragma unroll
        for (int r = 0; r < 4; r++) {
            int row = row0 + wm * 64 + i * 16 + quad * 4 + r;
            if (row >= Mv) continue;
            #pragma unroll
            for (int j = 0; j < NF; j++) {
                int col = col0 + wn * (BN / 2) + j * 16 + l15;
                float v = acc[i][j][r];
                if (addb) v += bias[col];
                unsafeAtomicAdd(&C[(size_t)row * N + col], v);
            }
        }
    }
}

// ------------------------------ LayerNorm (fp32 in, bf16 out) --------------
__global__ __launch_bounds__(256) void ln_bf16(
    const float* __restrict__ x, const float* __restrict__ g,
    const float* __restrict__ b, unsigned short* __restrict__ y, int M)
{
    int wid = threadIdx.x >> 6, lane = threadIdx.x & 63;
    int row = blockIdx.x * 4 + wid;
    if (row >= M) return;
    const float4* xr = (const float4*)(x + (size_t)row * DM);
    float4 v0 = xr[lane * 2], v1 = xr[lane * 2 + 1];
    float s  = v0.x + v0.y + v0.z + v0.w + v1.x + v1.y + v1.z + v1.w;
    float s2 = v0.x*v0.x + v0.y*v0.y + v0.z*v0.z + v0.w*v0.w
             + v1.x*v1.x + v1.y*v1.y + v1.z*v1.z + v1.w*v1.w;
    #pragma unroll
    for (int off = 32; off >= 1; off >>= 1) {
        s  += __shfl_xor(s, off);
        s2 += __shfl_xor(s2, off);
    }
    float mu = s * (1.f / DM);
    float var = s2 * (1.f / DM) - mu * mu;
    float r = rsqrtf(var + LN_EPS);
    const float4* gv = (const float4*)g;
    const float4* bv = (const float4*)b;
    unsigned int* yr = (unsigned int*)(y + (size_t)row * DM);
    #pragma unroll
    for (int i = 0; i < 2; i++) {
        float4 v = (i == 0) ? v0 : v1;
        float4 gg = gv[lane * 2 + i], bb = bv[lane * 2 + i];
        float ox = (v.x - mu) * r * gg.x + bb.x;
        float oy = (v.y - mu) * r * gg.y + bb.y;
        float oz = (v.z - mu) * r * gg.z + bb.z;
        float ow = (v.w - mu) * r * gg.w + bb.w;
        yr[lane * 4 + i * 2 + 0] = pack2(ox, oy);
        yr[lane * 4 + i * 2 + 1] = pack2(oz, ow);
    }
}

// ------------------------------ time attention -----------------------------
__global__ __launch_bounds__(256, 2) void time_attn(
    const unsigned short* __restrict__ qkv, unsigned short* __restrict__ out)
{
    int t = blockIdx.x * 256 + threadIdx.x;
    if (t >= 8 * NP) return;
    int h = t / NP, j = t - h * NP;
    int pos = j % 1200;
    union { bf16x8 v; unsigned short u[8]; } ld;
    float q[64];
    const unsigned short* qp = qkv + (size_t)(j + 1) * QKV_ST + h * 64;
    #pragma unroll
    for (int c = 0; c < 8; c++) {
        ld.v = *(const bf16x8*)(qp + c * 8);
        #pragma unroll
        for (int e = 0; e < 8; e++) q[c * 8 + e] = b2f(ld.u[e]) * 0.125f;
    }
    int rows[5] = {0, pos + 1, pos + 1201, pos + 2401, pos + 3601};
    float s[5];
    #pragma unroll
    for (int kk = 0; kk < 5; kk++) {
        const unsigned short* kp = qkv + (size_t)rows[kk] * QKV_ST + 512 + h * 64;
        float ss = 0.f;
        #pragma unroll
        for (int c = 0; c < 8; c++) {
            ld.v = *(const bf16x8*)(kp + c * 8);
            #pragma unroll
            for (int e = 0; e < 8; e++) ss += q[c * 8 + e] * b2f(ld.u[e]);
        }
        s[kk] = ss;
    }
    float mx = s[0];
    #pragma unroll
    for (int kk = 1; kk < 5; kk++) mx = fmaxf(mx, s[kk]);
    float e5[5], l = 0.f;
    #pragma unroll
    for (int kk = 0; kk < 5; kk++) { e5[kk] = __expf(s[kk] - mx); l += e5[kk]; }
    float rl = 1.f / l;
    float acc[64];
    #pragma unroll
    for (int d = 0; d < 64; d++) acc[d] = 0.f;
    #pragma unroll
    for (int kk = 0; kk < 5; kk++) {
        float p = e5[kk] * rl;
        const unsigned short* vp = qkv + (size_t)rows[kk] * QKV_ST + 1024 + h * 64;
        #pragma unroll
        for (int c = 0; c < 8; c++) {
            ld.v = *(const bf16x8*)(vp + c * 8);
            #pragma unroll
            for (int e = 0; e < 8; e++) acc[c * 8 + e] += p * b2f(ld.u[e]);
        }
    }
    unsigned int* op = (unsigned int*)(out + (size_t)(j + 1) * DM + h * 64);
    #pragma unroll
    for (int d2 = 0; d2 < 32; d2++) op[d2] = pack2(acc[2 * d2], acc[2 * d2 + 1]);
}

// ------------------------------ space attention (MFMA flash) ----------------
#define SPAD 72
__global__ __launch_bounds__(256, 2) void space_attn_mfma(
    const unsigned short* __restrict__ qkv, unsigned short* __restrict__ out)
{
    __shared__ short Ksm[64 * SPAD];
    __shared__ short VTsm[64 * SPAD];
    __shared__ short Psm[4][32 * SPAD];
    int qt = blockIdx.x, h = blockIdx.y, g = blockIdx.z;
    int f = g >> 1, half = g & 1;
    int tid = threadIdx.x, w = tid >> 6, lane = tid & 63;
    int l15 = lane & 15, quad = lane >> 4;

    int qrow_base = qt * 128 + w * 32;
    int qb = 1 + f * 1200 + half * 600;
    int kb = 1 + f * 1200 + (1 - half) * 600;

    bf16x8 aQ[2][2];
    #pragma unroll
    for (int mf = 0; mf < 2; mf++) {
        int qr = qrow_base + mf * 16 + l15;
        int qtok = qb + ((qr < 600) ? qr : 0);
        const unsigned short* qp = qkv + (size_t)qtok * QKV_ST + h * 64;
        #pragma unroll
        for (int ks = 0; ks < 2; ks++)
            aQ[mf][ks] = *(const bf16x8*)(qp + ks * 32 + quad * 8);
    }

    f32x4 O[2][4] = {};
    float mrow[2][4], lrow[2][4];
    #pragma unroll
    for (int mf = 0; mf < 2; mf++)
        #pragma unroll
        for (int r = 0; r < 4; r++) { mrow[mf][r] = -1e30f; lrow[mf][r] = 0.f; }

    for (int kt = 0; kt < 10; kt++) {
        __syncthreads();
        #pragma unroll
        for (int it = 0; it < 2; it++) {
            int c = tid + it * 256;
            int row = c >> 3, dc = (c & 7) * 8;
            int kidx = kt * 64 + row;
            int tok = (kidx == 0) ? 0 : ((kidx <= 600) ? kb + kidx - 1 : 0);
            const unsigned short* kp = qkv + (size_t)tok * QKV_ST + 512 + h * 64 + dc;
            *(bf16x8*)&Ksm[row * SPAD + dc] = *(const bf16x8*)kp;
            union { bf16x8 v; unsigned short u[8]; } vv;
            vv.v = *(const bf16x8*)(kp + 512);
            #pragma unroll
            for (int e = 0; e < 8; e++)
                VTsm[(dc + e) * SPAD + row] = vv.u[e];
        }
        __syncthreads();

        f32x4 S[2][4] = {};
        #pragma unroll
        for (int ks = 0; ks < 2; ks++) {
            bf16x8 bK[4];
            #pragma unroll
            for (int nf = 0; nf < 4; nf++)
                bK[nf] = *(const bf16x8*)&Ksm[(nf * 16 + l15) * SPAD + ks * 32 + quad * 8];
            #pragma unroll
            for (int mf = 0; mf < 2; mf++)
                #pragma unroll
                for (int nf = 0; nf < 4; nf++)
                    S[mf][nf] = __builtin_amdgcn_mfma_f32_16x16x32_bf16(
                                    aQ[mf][ks], bK[nf], S[mf][nf], 0, 0, 0);
        }

        #pragma unroll
        for (int mf = 0; mf < 2; mf++) {
            float pv[4][4];
            float lm[4] = {-1e30f, -1e30f, -1e30f, -1e30f};
            #pragma unroll
            for (int nf = 0; nf < 4; nf++) {
                int kidx = kt * 64 + nf * 16 + l15;
                bool valid = kidx <= 600;
                #pragma unroll
                for (int r = 0; r < 4; r++) {
                    float s = valid ? S[mf][nf][r] * 0.125f : -1e30f;
                    pv[nf][r] = s;
                    lm[r] = fmaxf(lm[r], s);
                }
            }
            #pragma unroll
            for (int off = 1; off < 16; off <<= 1)
                #pragma unroll
                for (int r = 0; r < 4; r++)
                    lm[r] = fmaxf(lm[r], __shfl_xor(lm[r], off));
            #pragma unroll
            for (int r = 0; r < 4; r++) {
                float nm = fmaxf(mrow[mf][r], lm[r]);
                float c = __expf(mrow[mf][r] - nm);
                mrow[mf][r] = nm;
                lrow[mf][r] *= c;
                #pragma unroll
                for (int nf = 0; nf < 4; nf++) O[mf][nf][r] *= c;
            }
            float rs[4] = {0.f, 0.f, 0.f, 0.f};
            #pragma unroll
            for (int nf = 0; nf < 4; nf++)
                #pragma unroll
                for (int r = 0; r < 4; r++) {
                    float p = __expf(pv[nf][r] - mrow[mf][r]);
                    pv[nf][r] = p;
                    rs[r] += p;
                }
            #pragma unroll
            for (int off = 1; off < 16; off <<= 1)
                #pragma unroll
                for (int r = 0; r < 4; r++)
                    rs[r] += __shfl_xor(rs[r], off);
            #pragma unroll
            for (int r = 0; r < 4; r++) lrow[mf][r] += rs[r];
            #pragma unroll
            for (int nf = 0; nf < 4; nf++)
                #pragma unroll
                for (int r = 0; r < 4; r++)
                    Psm[w][(mf * 16 + quad * 4 + r) * SPAD + nf * 16 + l15] = (short)f2b(pv[nf][r]);
        }
        asm volatile("s_waitcnt lgkmcnt(0)" ::: "memory");

        #pragma unroll
        for (int ks2 = 0; ks2 < 2; ks2++) {
            bf16x8 aP[2], bV[4];
            #pragma unroll
            for (int mf = 0; mf < 2; mf++)
                aP[mf] = *(const bf16x8*)&Psm[w][(mf * 16 + l15) * SPAD + ks2 * 32 + quad * 8];
            #pragma unroll
            for (int nf = 0; nf < 4; nf++)
                bV[nf] = *(const bf16x8*)&VTsm[(nf * 16 + l15) * SPAD + ks2 * 32 + quad * 8];
            #pragma unroll
            for (int mf = 0; mf < 2; mf++)
                #pragma unroll
                for (int nf = 0; nf < 4; nf++)
                    O[mf][nf] = __builtin_amdgcn_mfma_f32_16x16x32_bf16(
                                    aP[mf], bV[nf], O[mf][nf], 0, 0, 0);
        }
    }

    #pragma unroll
    for (int mf = 0; mf < 2; mf++)
        #pragma unroll
        for (int r = 0; r < 4; r++) {
            int qr = qrow_base + mf * 16 + quad * 4 + r;
            if (qr >= 600) continue;
            int qtok = qb + qr;
            float rl = 1.f / lrow[mf][r];
            #pragma unroll
            for (int nf = 0; nf < 4; nf++)
                out[(size_t)qtok * DM + h * 64 + nf * 16 + l15] = f2b(O[mf][nf][r] * rl);
        }
}

// ------------------------------ cls attention (split-K) --------------------
__global__ __launch_bounds__(256) void cls_attn_part(
    const unsigned short* __restrict__ qkv, float* __restrict__ part)
{
    int ch = blockIdx.x, h = blockIdx.y;
    int wid = threadIdx.x >> 6, lane = threadIdx.x & 63;
    __shared__ float sm[4], sl[4], sa[4][64];
    float qv = b2f(qkv[h * 64 + lane]) * 0.125f;
    int k0 = ch * 100 + wid * 25;
    float m = -1e30f, l = 0.f, acc = 0.f;
    for (int i = 0; i < 25; i += 2) {
        int key0 = k0 + i, key1 = key0 + 1;
        bool ok0 = key0 < NT;
        bool ok1 = (i + 1 < 25) && (key1 < NT);
        const unsigned short* kr0 = qkv + (size_t)(ok0 ? key0 : 0) * QKV_ST + 512 + h * 64;
        const unsigned short* kr1 = qkv + (size_t)(ok1 ? key1 : 0) * QKV_ST + 512 + h * 64;
        float s0 = qv * b2f(kr0[lane]);
        float v0 = b2f(kr0[512 + lane]);
        float s1 = qv * b2f(kr1[lane]);
        float v1 = b2f(kr1[512 + lane]);
        #pragma unroll
        for (int off = 32; off >= 1; off >>= 1) {
            s0 += __shfl_xor(s0, off);
            s1 += __shfl_xor(s1, off);
        }
        float nm = m;
        if (ok0) nm = fmaxf(nm, s0);
        if (ok1) nm = fmaxf(nm, s1);
        float c  = __expf(m - nm);
        float p0 = ok0 ? __expf(s0 - nm) : 0.f;
        float p1 = ok1 ? __expf(s1 - nm) : 0.f;
        l   = l * c + p0 + p1;
        acc = acc * c + p0 * v0 + p1 * v1;
        m = nm;
    }
    if (lane == 0) { sm[wid] = m; sl[wid] = l; }
    sa[wid][lane] = acc;
    __syncthreads();
    if (wid == 0) {
        float M2 = fmaxf(fmaxf(sm[0], sm[1]), fmaxf(sm[2], sm[3]));
        float L = 0.f, o = 0.f;
        #pragma unroll
        for (int w = 0; w < 4; w++) {
            float c = __expf(sm[w] - M2);
            L += sl[w] * c;
            o += sa[w][lane] * c;
        }
        float* p = part + ((size_t)h * NCH + ch) * 68;
        if (lane == 0) { p[0] = M2; p[1] = L; }
        p[4 + lane] = o;
    }
}

__global__ __launch_bounds__(64) void cls_attn_reduce(
    const float* __restrict__ part, unsigned short* __restrict__ out)
{
    int h = blockIdx.x, lane = threadIdx.x;
    float m = -1e30f, l = 0.f, acc = 0.f;
    for (int c = 0; c < NCH; c++) {
        const float* p = part + ((size_t)h * NCH + c) * 68;
        float cm = p[0], cl = p[1], ca = p[4 + lane];
        float nm = fmaxf(m, cm);
        float e1 = __expf(m - nm), e2 = __expf(cm - nm);
        l   = l * e1 + cl * e2;
        acc = acc * e1 + ca * e2;
        m = nm;
    }
    out[h * 64 + lane] = f2b(acc / l);
}

// ------------------------------ GeGLU (bf16 in/out) ------------------------
__global__ __launch_bounds__(256) void geglu_kernel(
    const unsigned short* __restrict__ h, unsigned short* __restrict__ out)
{
    int idx = blockIdx.x * 256 + threadIdx.x;
    if (idx >= NT * 256) return;
    int r = idx >> 8, cc = (idx & 255) * 8;
    const unsigned short* up = h + (size_t)r * 4096 + cc;
    const unsigned short* gp = up + 2048;
    float o[8];
    #pragma unroll
    for (int e = 0; e < 8; e++) {
        float u = b2f(up[e]), gg = b2f(gp[e]);
        o[e] = u * 0.5f * gg * (1.f + erff(gg * 0.70710678f));
    }
    unsigned int* op = (unsigned int*)(out + (size_t)r * 2048 + cc);
    #pragma unroll
    for (int e = 0; e < 4; e++) op[e] = pack2(o[2 * e], o[2 * e + 1]);
}

// ------------------------------ head ---------------------------------------
__global__ __launch_bounds__(64) void head_kernel(
    const float* __restrict__ x, const float* __restrict__ g,
    const float* __restrict__ b, const float* __restrict__ w,
    const float* __restrict__ ob, float* __restrict__ out)
{
    __shared__ float xn[DM];
    int lane = threadIdx.x;
    const float4* xr = (const float4*)x;
    float4 v0 = xr[lane * 2], v1 = xr[lane * 2 + 1];
    float s  = v0.x + v0.y + v0.z + v0.w + v1.x + v1.y + v1.z + v1.w;
    float s2 = v0.x*v0.x + v0.y*v0.y + v0.z*v0.z + v0.w*v0.w
             + v1.x*v1.x + v1.y*v1.y + v1.z*v1.z + v1.w*v1.w;
    #pragma unroll
    for (int off = 32; off >= 1; off >>= 1) {
        s  += __shfl_xor(s, off);
        s2 += __shfl_xor(s2, off);
    }
    float mu = s * (1.f / DM);
    float var = s2 * (1.f / DM) - mu * mu;
    float r = rsqrtf(var + LN_EPS);
    #pragma unroll
    for (int i = 0; i < 8; i++) {
        int d = lane * 8 + i;
        xn[d] = (x[d] - mu) * r * g[d] + b[d];
    }
    __syncthreads();
    if (lane < 60) {
        float a = ob[lane];
        for (int d = 0; d < DM; d++) a += xn[d] * w[d * 60 + lane];
        out[lane] = a;
    }
}

// ------------------------------ driver -------------------------------------
extern "C" void kernel_launch(void* const* d_in, const int* in_sizes, int n_in,
                              void* d_out, int out_size, void* d_ws, size_t ws_size,
                              hipStream_t stream)
{
    const float* video     = (const float*)d_in[0];
    const float* patch_w   = (const float*)d_in[1];
    const float* patch_b   = (const float*)d_in[2];
    const float* pos_emb   = (const float*)d_in[3];
    const float* cls_token = (const float*)d_in[4];
    const float* t_ln_g    = (const float*)d_in[5];
    const float* t_ln_b    = (const float*)d_in[6];
    const float* t_qkv_w   = (const float*)d_in[7];
    const float* t_out_w   = (const float*)d_in[8];
    const float* t_out_b   = (const float*)d_in[9];
    const float* s_ln_g    = (const float*)d_in[10];
    const float* s_ln_b    = (const float*)d_in[11];
    const float* s_qkv_w   = (const float*)d_in[12];
    const float* s_out_w   = (const float*)d_in[13];
    const float* s_out_b   = (const float*)d_in[14];
    const float* f_ln_g    = (const float*)d_in[15];
    const float* f_ln_b    = (const float*)d_in[16];
    const float* f_w1      = (const float*)d_in[17];
    const float* f_b1      = (const float*)d_in[18];
    const float* f_w2      = (const float*)d_in[19];
    const float* f_b2      = (const float*)d_in[20];
    const float* o_ln_g    = (const float*)d_in[21];
    const float* o_ln_b    = (const float*)d_in[22];
    const float* o_w       = (const float*)d_in[23];
    const float* o_b       = (const float*)d_in[24];

    char* ws = (char*)d_ws;
    size_t o = 0;
    float*          X    = (float*)(ws + o);          o += (size_t)(MP + 1) * 512 * 4;
    unsigned short* XN   = (unsigned short*)(ws + o); o += (size_t)MP * 512 * 2;
    unsigned short* QKV  = (unsigned short*)(ws + o); o += (size_t)MP * 1536 * 2;
    unsigned short* H16  = (unsigned short*)(ws + o); o += (size_t)MP * 4096 * 2;
    unsigned short* MID  = (unsigned short*)(ws + o); o += (size_t)MP * 2048 * 2;
    unsigned short* PT   = (unsigned short*)(ws + o); o += (size_t)MP * 768 * 2;
    unsigned short* W16  = (unsigned short*)(ws + o); o += (size_t)5242880 * 2;
    unsigned short* PW16 = (unsigned short*)(ws + o); o += (size_t)512 * 768 * 2;
    float*          CP   = (float*)(ws + o);          o += (size_t)8 * NCH * 68 * 4;

    // ---- patch embed + cls + pos ----
    patchify_kernel<<<(NP * 768 + 255) / 256, 256, 0, stream>>>(video, PT);
    cls_init_kernel<<<2, 256, 0, stream>>>(cls_token, pos_emb, X);
    posx_init<<<NP * DM / 4 / 256, 256, 0, stream>>>(pos_emb, X);
    convertT_one<<<(768 / 32) * (512 / 32), 256, 0, stream>>>(patch_w, PW16, 768, 512);
    mfma_gemm_sk<128, 3><<<dim3(4, 19, 3), 512, 0, stream>>>(PT, PW16, patch_b,
                                                             X + DM, NP, DM, 768);

    dim3 g_qkv(12, 19), g_ff1(16, 19);
    dim3 g_out_sk(4, 19, 4), g_ff2_sk(4, 19, 4);
    for (int i = 0; i < 12; i++) {
        convertT_layer<<<5120, 256, 0, stream>>>(
            t_qkv_w + (size_t)i * 512 * 1536, t_out_w + (size_t)i * 512 * 512,
            s_qkv_w + (size_t)i * 512 * 1536, s_out_w + (size_t)i * 512 * 512,
            f_w1 + (size_t)i * 512 * 4096, f_w2 + (size_t)i * 2048 * 512, W16);

        // ---- time attention block ----
        ln_bf16<<<1201, 256, 0, stream>>>(X, t_ln_g + i * DM, t_ln_b + i * DM, XN, NT);
        mfma_gemm<128, true><<<g_qkv, 512, 0, stream>>>(XN, W16 + 0, nullptr, nullptr,
                                                        QKV, NT, QKV_ST, DM);
        time_attn<<<150, 256, 0, stream>>>(QKV, MID);
        cls_attn_part<<<dim3(NCH, 8), 256, 0, stream>>>(QKV, CP);
        cls_attn_reduce<<<8, 64, 0, stream>>>(CP, MID);
        mfma_gemm_sk<128, 4><<<g_out_sk, 512, 0, stream>>>(MID, W16 + 786432,
                                                           t_out_b + i * DM, X, NT, DM, DM);
        // ---- space attention block ----
        ln_bf16<<<1201, 256, 0, stream>>>(X, s_ln_g + i * DM, s_ln_b + i * DM, XN, NT);
        mfma_gemm<128, true><<<g_qkv, 512, 0, stream>>>(XN, W16 + 1048576, nullptr, nullptr,
                                                        QKV, NT, QKV_ST, DM);
        space_attn_mfma<<<dim3(5, 8, 8), 256, 0, stream>>>(QKV, MID);
        cls_attn_part<<<dim3(NCH, 8), 256, 0, stream>>>(QKV, CP);
        cls_attn_reduce<<<8, 64, 0, stream>>>(CP, MID);
        mfma_gemm_sk<128, 4><<<g_out_sk, 512, 0, stream>>>(MID, W16 + 1835008,
                                                           s_out_b + i * DM, X, NT, DM, DM);
        // ---- GeGLU FF block ----
        ln_bf16<<<1201, 256, 0, stream>>>(X, f_ln_g + i * DM, f_ln_b + i * DM, XN, NT);
        mfma_gemm<256, true><<<g_ff1, 512, 0, stream>>>(XN, W16 + 2097152, f_b1 + i * 4096,
                                                        nullptr, H16, NT, 4096, DM);
        geglu_kernel<<<(NT * 256 + 255) / 256, 256, 0, stream>>>(H16, MID);
        mfma_gemm_sk<128, 4><<<g_ff2_sk, 512, 0, stream>>>(MID, W16 + 4194304,
                                                           f_b2 + i * DM, X, NT, DM, 2048);
    }

    head_kernel<<<1, 64, 0, stream>>>(X, o_ln_g, o_ln_b, o_w, o_b, (float*)d_out);
}

// Round 4
// 4382.643 us; speedup vs baseline: 1.3692x; 1.3692x over previous
//
#include <hip/hip_runtime.h>
#include <cmath>

// ---------------------------------------------------------------------------
// MutualTimeSformer — round 7: R1 base + (a) counted-vmcnt dbuf GEMM (waits
// for PREVIOUS tile's loads, not the just-issued ones), (b) XCD-bijective
// block remap for L2-local A panels, (c) FF1+GeGLU fusion, (d) 4-way d-split
// time attention, (e) split-K patch embed.
// Dims: B=1, F=4, n=1200/frame, N=4801 tokens (pad 4864), D=512, H=8, DH=64
// ---------------------------------------------------------------------------

#define NT      4801
#define NP      4800
#define MP      4864          // padded row count (38 * 128)
#define DM      512
#define QKV_ST  1536
#define LN_EPS  1e-5f
#define NCH     49            // cls split-K chunks (49*100 >= 4801)

typedef __attribute__((ext_vector_type(8))) short bf16x8;
typedef __attribute__((ext_vector_type(4))) float f32x4;

__device__ __forceinline__ unsigned short f2b(float f) {
    union { float f; unsigned int u; } x; x.f = f;
    unsigned int r = (x.u + 0x7FFFu + ((x.u >> 16) & 1u)) >> 16;
    return (unsigned short)r;
}
__device__ __forceinline__ float b2f(unsigned short b) {
    union { unsigned int u; float f; } x; x.u = ((unsigned int)b) << 16;
    return x.f;
}
__device__ __forceinline__ unsigned int pack2(float a, float b) {
    return (unsigned int)f2b(a) | ((unsigned int)f2b(b) << 16);
}

__device__ __forceinline__ void gl_lds16(const void* g, void* l) {
    __builtin_amdgcn_global_load_lds(
        (__attribute__((address_space(1))) unsigned int*)(unsigned long long)(uintptr_t)g,
        (__attribute__((address_space(3))) unsigned int*)l, 16, 0, 0);
}

// bijective XCD-chunk remap (m204): consecutive logical ids (x fastest) land
// on one XCD -> blocks sharing an A row-panel share an L2.
__device__ __forceinline__ void xcd_remap(int& bx, int& by, int& bz) {
    const int gx = gridDim.x, gy = gridDim.y;
    const int nwg = gx * gy * gridDim.z;
    const int orig = (blockIdx.z * gy + blockIdx.y) * gx + blockIdx.x;
    const int q = nwg >> 3, r = nwg & 7;
    const int xcd = orig & 7, idx = orig >> 3;
    const int id = (xcd < r ? xcd * (q + 1) : r * (q + 1) + (xcd - r) * q) + idx;
    bx = id % gx;
    const int t = id / gx;
    by = t % gy;
    bz = t / gy;
}

// ------------------------------ patchify (fp32 -> bf16) --------------------
__global__ void patchify_kernel(const float* __restrict__ video, unsigned short* __restrict__ out)
{
    int idx = blockIdx.x * 256 + threadIdx.x;
    if (idx >= NP * 768) return;
    int tok = idx / 768, e = idx % 768;
    int c  = e % 3;
    int pe = e / 3;
    int p2 = pe % 16, p1 = pe / 16;
    int half = tok / 2400, r = tok % 2400;
    int f = r / 600, rr = r % 600;
    int hi = rr / 20, wi = rr % 20;
    int row = hi * 16 + p1;
    int col = half * 320 + wi * 16 + p2;
    out[idx] = f2b(video[(((size_t)f * 3 + c) * 480 + row) * 640 + col]);
}

__global__ void cls_init_kernel(const float* __restrict__ cls_token,
                                const float* __restrict__ pos, float* __restrict__ X)
{
    int d = blockIdx.x * 256 + threadIdx.x;
    if (d < DM) X[d] = cls_token[d] + pos[d];
}

// pre-init X rows 1..4800 with pos_emb (patch GEMM atomically accumulates)
__global__ void posx_init(const float* __restrict__ pos, float* __restrict__ X)
{
    int i = blockIdx.x * 256 + threadIdx.x;
    if (i < NP * DM / 4)
        ((float4*)(X + DM))[i] = ((const float4*)(pos + DM))[i];
}

// ------------------------------ weight transpose-convert -------------------
__device__ __forceinline__ void transpose_tile(const float* __restrict__ in,
                                               unsigned short* __restrict__ out,
                                               int K, int N, int tile)
{
    __shared__ float T[32][33];
    int ntk = K / 32;
    int kt = tile % ntk, nt = tile / ntk;
    int k0 = kt * 32, n0 = nt * 32;
    int tx = threadIdx.x & 31, ty = threadIdx.x >> 5;
    #pragma unroll
    for (int i = 0; i < 4; i++)
        T[ty + 8 * i][tx] = in[(size_t)(k0 + ty + 8 * i) * N + n0 + tx];
    __syncthreads();
    #pragma unroll
    for (int i = 0; i < 4; i++)
        out[(size_t)(n0 + ty + 8 * i) * K + k0 + tx] = f2b(T[tx][ty + 8 * i]);
}

__global__ __launch_bounds__(256) void convertT_layer(
    const float* __restrict__ w0, const float* __restrict__ w1,
    const float* __restrict__ w2, const float* __restrict__ w3,
    const float* __restrict__ w4, const float* __restrict__ w5,
    unsigned short* __restrict__ out)
{
    int t = blockIdx.x;
    if      (t <  768) transpose_tile(w0, out + 0,       512, 1536, t);
    else if (t < 1024) transpose_tile(w1, out + 786432,  512,  512, t - 768);
    else if (t < 1792) transpose_tile(w2, out + 1048576, 512, 1536, t - 1024);
    else if (t < 2048) transpose_tile(w3, out + 1835008, 512,  512, t - 1792);
    else if (t < 4096) transpose_tile(w4, out + 2097152, 512, 4096, t - 2048);
    else               transpose_tile(w5, out + 4194304, 2048, 512, t - 4096);
}

__global__ __launch_bounds__(256) void convertT_one(
    const float* __restrict__ in, unsigned short* __restrict__ out, int K, int N)
{
    transpose_tile(in, out, K, N, blockIdx.x);
}

// -------------------- MFMA GEMM (128x128, counted-vmcnt dbuf) --------------
template<bool OB16>
__global__ __launch_bounds__(256, 2) void mfma_gemm(
    const unsigned short* __restrict__ A, const unsigned short* __restrict__ BT,
    const float* __restrict__ bias, const float* __restrict__ add,
    void* __restrict__ C, int Mv, int N, int K)
{
    __shared__ short Asm[2][128 * 64];
    __shared__ short Bsm[2][128 * 64];
    int bx, by, bz; xcd_remap(bx, by, bz); (void)bz;
    const int tid = threadIdx.x, w = tid >> 6, lane = tid & 63;
    const int row0 = by * 128, col0 = bx * 128;
    const int wm = w >> 1, wn = w & 1;
    const int l15 = lane & 15, quad = lane >> 4;

    f32x4 acc[4][4] = {};

    int ar[4], aq[4];
    #pragma unroll
    for (int i = 0; i < 4; i++) {
        int c = (w * 4 + i) * 64 + lane;
        ar[i] = c >> 3;
        aq[i] = (c & 7) ^ ((c >> 3) & 7);
    }
    const unsigned short* Ab = A  + (size_t)row0 * K;
    const unsigned short* Bb = BT + (size_t)col0 * K;

    // prologue: stage k-tile 0 into buffer 0 (8 vm ops/thread)
    #pragma unroll
    for (int i = 0; i < 4; i++) {
        gl_lds16(Ab + (size_t)ar[i] * K + aq[i] * 8, &Asm[0][(w * 4 + i) * 512]);
        gl_lds16(Bb + (size_t)ar[i] * K + aq[i] * 8, &Bsm[0][(w * 4 + i) * 512]);
    }

    const int nt = K >> 6;
    int cur = 0;
    for (int t = 0; t < nt; t++) {
        if (t + 1 < nt) {
            const int k0 = (t + 1) << 6;
            #pragma unroll
            for (int i = 0; i < 4; i++) {
                gl_lds16(Ab + (size_t)ar[i] * K + k0 + aq[i] * 8,
                         &Asm[cur ^ 1][(w * 4 + i) * 512]);
                gl_lds16(Bb + (size_t)ar[i] * K + k0 + aq[i] * 8,
                         &Bsm[cur ^ 1][(w * 4 + i) * 512]);
            }
            // wait only for tile t (the 8 newest ops stay in flight)
            asm volatile("s_waitcnt vmcnt(8)\ns_barrier" ::: "memory");
        } else {
            asm volatile("s_waitcnt vmcnt(0)\ns_barrier" ::: "memory");
        }
        const short* As = Asm[cur];
        const short* Bs = Bsm[cur];
        #pragma unroll
        for (int ks = 0; ks < 2; ks++) {
            bf16x8 af[4], bfr[4];
            #pragma unroll
            for (int i = 0; i < 4; i++) {
                int m  = wm * 64 + i * 16 + l15;
                af[i]  = *(const bf16x8*)&As[m * 64 + (((ks * 4 + quad) ^ (m & 7))) * 8];
                int n  = wn * 64 + i * 16 + l15;
                bfr[i] = *(const bf16x8*)&Bs[n * 64 + (((ks * 4 + quad) ^ (n & 7))) * 8];
            }
            #pragma unroll
            for (int i = 0; i < 4; i++)
                #pragma unroll
                for (int j = 0; j < 4; j++)
                    acc[i][j] = __builtin_amdgcn_mfma_f32_16x16x32_bf16(
                                    af[i], bfr[j], acc[i][j], 0, 0, 0);
        }
        asm volatile("s_barrier" ::: "memory");  // protect buf before next stage
        cur ^= 1;
    }

    #pragma unroll
    for (int i = 0; i < 4; i++) {
        #pragma unroll
        for (int r = 0; r < 4; r++) {
            int row = row0 + wm * 64 + i * 16 + quad * 4 + r;
            if (row >= Mv) continue;
            #pragma unroll
            for (int j = 0; j < 4; j++) {
                int col = col0 + wn * 64 + j * 16 + l15;
                float v = acc[i][j][r];
                if (bias) v += bias[col];
                if (add)  v += add[(size_t)row * N + col];
                if (OB16) ((unsigned short*)C)[(size_t)row * N + col] = f2b(v);
                else      ((float*)C)[(size_t)row * N + col] = v;
            }
        }
    }
}

// ------------- split-K MFMA GEMM (fp32 atomics, counted-vmcnt dbuf) --------
// C pre-initialized with the additive term. bias added by kz==0 split only.
template<int SPLITS>
__global__ __launch_bounds__(256, 2) void mfma_gemm_sk(
    const unsigned short* __restrict__ A, const unsigned short* __restrict__ BT,
    const float* __restrict__ bias, float* __restrict__ C, int Mv, int N, int K)
{
    __shared__ short Asm[2][128 * 64];
    __shared__ short Bsm[2][128 * 64];
    int bx, by, bz; xcd_remap(bx, by, bz);
    const int tid = threadIdx.x, w = tid >> 6, lane = tid & 63;
    const int row0 = by * 128, col0 = bx * 128;
    const int wm = w >> 1, wn = w & 1;
    const int l15 = lane & 15, quad = lane >> 4;
    const int kchunk = K / SPLITS;
    const int kbeg = bz * kchunk;

    f32x4 acc[4][4] = {};

    int ar[4], aq[4];
    #pragma unroll
    for (int i = 0; i < 4; i++) {
        int c = (w * 4 + i) * 64 + lane;
        ar[i] = c >> 3;
        aq[i] = (c & 7) ^ ((c >> 3) & 7);
    }
    const unsigned short* Ab = A  + (size_t)row0 * K + kbeg;
    const unsigned short* Bb = BT + (size_t)col0 * K + kbeg;

    #pragma unroll
    for (int i = 0; i < 4; i++) {
        gl_lds16(Ab + (size_t)ar[i] * K + aq[i] * 8, &Asm[0][(w * 4 + i) * 512]);
        gl_lds16(Bb + (size_t)ar[i] * K + aq[i] * 8, &Bsm[0][(w * 4 + i) * 512]);
    }

    const int nt = kchunk >> 6;
    int cur = 0;
    for (int t = 0; t < nt; t++) {
        if (t + 1 < nt) {
            const int k0 = (t + 1) << 6;
            #pragma unroll
            for (int i = 0; i < 4; i++) {
                gl_lds16(Ab + (size_t)ar[i] * K + k0 + aq[i] * 8,
                         &Asm[cur ^ 1][(w * 4 + i) * 512]);
                gl_lds16(Bb + (size_t)ar[i] * K + k0 + aq[i] * 8,
                         &Bsm[cur ^ 1][(w * 4 + i) * 512]);
            }
            asm volatile("s_waitcnt vmcnt(8)\ns_barrier" ::: "memory");
        } else {
            asm volatile("s_waitcnt vmcnt(0)\ns_barrier" ::: "memory");
        }
        const short* As = Asm[cur];
        const short* Bs = Bsm[cur];
        #pragma unroll
        for (int ks = 0; ks < 2; ks++) {
            bf16x8 af[4], bfr[4];
            #pragma unroll
            for (int i = 0; i < 4; i++) {
                int m  = wm * 64 + i * 16 + l15;
                af[i]  = *(const bf16x8*)&As[m * 64 + (((ks * 4 + quad) ^ (m & 7))) * 8];
                int n  = wn * 64 + i * 16 + l15;
                bfr[i] = *(const bf16x8*)&Bs[n * 64 + (((ks * 4 + quad) ^ (n & 7))) * 8];
            }
            #pragma unroll
            for (int i = 0; i < 4; i++)
                #pragma unroll
                for (int j = 0; j < 4; j++)
                    acc[i][j] = __builtin_amdgcn_mfma_f32_16x16x32_bf16(
                                    af[i], bfr[j], acc[i][j], 0, 0, 0);
        }
        asm volatile("s_barrier" ::: "memory");
        cur ^= 1;
    }

    const bool addb = (bz == 0) && (bias != nullptr);
    #pragma unroll
    for (int i = 0; i < 4; i++) {
        #pragma unroll
        for (int r = 0; r < 4; r++) {
            int row = row0 + wm * 64 + i * 16 + quad * 4 + r;
            if (row >= Mv) continue;
            #pragma unroll
            for (int j = 0; j < 4; j++) {
                int col = col0 + wn * 64 + j * 16 + l15;
                float v = acc[i][j][r];
                if (addb) v += bias[col];
                unsafeAtomicAdd(&C[(size_t)row * N + col], v);
            }
        }
    }
}

// -------------- FF1 + GeGLU fused (u-tile and g-tile per block) ------------
// A: XN [MP,512] bf16; BT: [4096,512] bf16 (row = output col). Block (bx,by)
// computes rows by*128, u-cols bx*128 and g-cols bx*128+2048, writes
// geglu(u,g) bf16 directly to out[row*2048 + ucol]. Grid (16, 38).
__global__ __launch_bounds__(256, 2) void mfma_ff1_geglu(
    const unsigned short* __restrict__ A, const unsigned short* __restrict__ BT,
    const float* __restrict__ b1, unsigned short* __restrict__ out, int Mv)
{
    __shared__ short Asm[128 * 64];
    __shared__ short Bu[128 * 64];
    __shared__ short Bg[128 * 64];
    int bx, by, bz; xcd_remap(bx, by, bz); (void)bz;
    const int tid = threadIdx.x, w = tid >> 6, lane = tid & 63;
    const int row0 = by * 128, colu0 = bx * 128;
    const int wm = w >> 1, wn = w & 1;
    const int l15 = lane & 15, quad = lane >> 4;

    f32x4 au[4][4] = {};
    f32x4 ag[4][4] = {};

    int ar[4], aq[4];
    #pragma unroll
    for (int i = 0; i < 4; i++) {
        int c = (w * 4 + i) * 64 + lane;
        ar[i] = c >> 3;
        aq[i] = (c & 7) ^ ((c >> 3) & 7);
    }
    const unsigned short* Ab  = A  + (size_t)row0 * 512;
    const unsigned short* Bub = BT + (size_t)colu0 * 512;
    const unsigned short* Bgb = BT + (size_t)(colu0 + 2048) * 512;

    for (int k0 = 0; k0 < 512; k0 += 64) {
        #pragma unroll
        for (int i = 0; i < 4; i++) {
            gl_lds16(Ab  + (size_t)ar[i] * 512 + k0 + aq[i] * 8, &Asm[(w * 4 + i) * 512]);
            gl_lds16(Bub + (size_t)ar[i] * 512 + k0 + aq[i] * 8, &Bu[(w * 4 + i) * 512]);
            gl_lds16(Bgb + (size_t)ar[i] * 512 + k0 + aq[i] * 8, &Bg[(w * 4 + i) * 512]);
        }
        __syncthreads();   // full drain (vmcnt0) + barrier
        #pragma unroll
        for (int ks = 0; ks < 2; ks++) {
            bf16x8 af[4], bu[4], bg[4];
            #pragma unroll
            for (int i = 0; i < 4; i++) {
                int m = wm * 64 + i * 16 + l15;
                int p = (((ks * 4 + quad) ^ (m & 7))) * 8;
                af[i] = *(const bf16x8*)&Asm[m * 64 + p];
                int n = wn * 64 + i * 16 + l15;
                int pb = (((ks * 4 + quad) ^ (n & 7))) * 8;
                bu[i] = *(const bf16x8*)&Bu[n * 64 + pb];
                bg[i] = *(const bf16x8*)&Bg[n * 64 + pb];
            }
            #pragma unroll
            for (int i = 0; i < 4; i++)
                #pragma unroll
                for (int j = 0; j < 4; j++) {
                    au[i][j] = __builtin_amdgcn_mfma_f32_16x16x32_bf16(
                                   af[i], bu[j], au[i][j], 0, 0, 0);
                    ag[i][j] = __builtin_amdgcn_mfma_f32_16x16x32_bf16(
                                   af[i], bg[j], ag[i][j], 0, 0, 0);
                }
        }
        __syncthreads();   // reads done before next overwrite
    }

    #pragma unroll
    for (int i = 0; i < 4; i++) {
        #pragma unroll
        for (int r = 0; r < 4; r++) {
            int row = row0 + wm * 64 + i * 16 + quad * 4 + r;
            if (row >= Mv) continue;
            #pragma unroll
            for (int j = 0; j < 4; j++) {
                int col = colu0 + wn * 64 + j * 16 + l15;
                float u = au[i][j][r] + b1[col];
                float g = ag[i][j][r] + b1[col + 2048];
                float h = u * 0.5f * g * (1.f + erff(g * 0.70710678f));
                out[(size_t)row * 2048 + col] = f2b(h);
            }
        }
    }
}

// ------------------------------ LayerNorm (fp32 in, bf16 out) --------------
__global__ __launch_bounds__(256) void ln_bf16(
    const float* __restrict__ x, const float* __restrict__ g,
    const float* __restrict__ b, unsigned short* __restrict__ y, int M)
{
    int wid = threadIdx.x >> 6, lane = threadIdx.x & 63;
    int row = blockIdx.x * 4 + wid;
    if (row >= M) return;
    const float4* xr = (const float4*)(x + (size_t)row * DM);
    float4 v0 = xr[lane * 2], v1 = xr[lane * 2 + 1];
    float s  = v0.x + v0.y + v0.z + v0.w + v1.x + v1.y + v1.z + v1.w;
    float s2 = v0.x*v0.x + v0.y*v0.y + v0.z*v0.z + v0.w*v0.w
             + v1.x*v1.x + v1.y*v1.y + v1.z*v1.z + v1.w*v1.w;
    #pragma unroll
    for (int off = 32; off >= 1; off >>= 1) {
        s  += __shfl_xor(s, off);
        s2 += __shfl_xor(s2, off);
    }
    float mu = s * (1.f / DM);
    float var = s2 * (1.f / DM) - mu * mu;
    float r = rsqrtf(var + LN_EPS);
    const float4* gv = (const float4*)g;
    const float4* bv = (const float4*)b;
    unsigned int* yr = (unsigned int*)(y + (size_t)row * DM);
    #pragma unroll
    for (int i = 0; i < 2; i++) {
        float4 v = (i == 0) ? v0 : v1;
        float4 gg = gv[lane * 2 + i], bb = bv[lane * 2 + i];
        float ox = (v.x - mu) * r * gg.x + bb.x;
        float oy = (v.y - mu) * r * gg.y + bb.y;
        float oz = (v.z - mu) * r * gg.z + bb.z;
        float ow = (v.w - mu) * r * gg.w + bb.w;
        yr[lane * 4 + i * 2 + 0] = pack2(ox, oy);
        yr[lane * 4 + i * 2 + 1] = pack2(oz, ow);
    }
}

// ---------------- time attention (4-way d-split, 600 blocks) ---------------
// lane group of 4 = one token: dq = tid&3 handles dims [dq*16, dq*16+16).
// Partial dots reduced via shfl_xor(1,2). Coalesced: 4 lanes = 128B.
__global__ __launch_bounds__(256, 4) void time_attn4(
    const unsigned short* __restrict__ qkv, unsigned short* __restrict__ out)
{
    int tid = threadIdx.x;
    int dq = tid & 3, tl = tid >> 2;
    int b = blockIdx.x;
    int h = b / 75;
    int j = (b - h * 75) * 64 + tl;          // 0..4799
    int pos = j % 1200;
    int d0 = dq * 16;
    union { bf16x8 v; unsigned short u[8]; } ld;
    float q[16];
    const unsigned short* qp = qkv + (size_t)(j + 1) * QKV_ST + h * 64 + d0;
    #pragma unroll
    for (int c = 0; c < 2; c++) {
        ld.v = *(const bf16x8*)(qp + c * 8);
        #pragma unroll
        for (int e = 0; e < 8; e++) q[c * 8 + e] = b2f(ld.u[e]) * 0.125f;
    }
    int rows[5] = {0, pos + 1, pos + 1201, pos + 2401, pos + 3601};
    float s[5];
    #pragma unroll
    for (int kk = 0; kk < 5; kk++) {
        const unsigned short* kp = qkv + (size_t)rows[kk] * QKV_ST + 512 + h * 64 + d0;
        float ss = 0.f;
        #pragma unroll
        for (int c = 0; c < 2; c++) {
            ld.v = *(const bf16x8*)(kp + c * 8);
            #pragma unroll
            for (int e = 0; e < 8; e++) ss += q[c * 8 + e] * b2f(ld.u[e]);
        }
        ss += __shfl_xor(ss, 1);
        ss += __shfl_xor(ss, 2);
        s[kk] = ss;
    }
    float mx = s[0];
    #pragma unroll
    for (int kk = 1; kk < 5; kk++) mx = fmaxf(mx, s[kk]);
    float e5[5], l = 0.f;
    #pragma unroll
    for (int kk = 0; kk < 5; kk++) { e5[kk] = __expf(s[kk] - mx); l += e5[kk]; }
    float rl = 1.f / l;
    float acc[16];
    #pragma unroll
    for (int d = 0; d < 16; d++) acc[d] = 0.f;
    #pragma unroll
    for (int kk = 0; kk < 5; kk++) {
        float p = e5[kk] * rl;
        const unsigned short* vp = qkv + (size_t)rows[kk] * QKV_ST + 1024 + h * 64 + d0;
        #pragma unroll
        for (int c = 0; c < 2; c++) {
            ld.v = *(const bf16x8*)(vp + c * 8);
            #pragma unroll
            for (int e = 0; e < 8; e++) acc[c * 8 + e] += p * b2f(ld.u[e]);
        }
    }
    unsigned int* op = (unsigned int*)(out + (size_t)(j + 1) * DM + h * 64 + d0);
    #pragma unroll
    for (int d2 = 0; d2 < 8; d2++) op[d2] = pack2(acc[2 * d2], acc[2 * d2 + 1]);
}

// ------------------------------ space attention (MFMA flash) ----------------
#define SPAD 72
__global__ __launch_bounds__(256, 2) void space_attn_mfma(
    const unsigned short* __restrict__ qkv, unsigned short* __restrict__ out)
{
    __shared__ short Ksm[64 * SPAD];
    __shared__ short VTsm[64 * SPAD];
    __shared__ short Psm[4][32 * SPAD];
    int qt = blockIdx.x, h = blockIdx.y, g = blockIdx.z;
    int f = g >> 1, half = g & 1;
    int tid = threadIdx.x, w = tid >> 6, lane = tid & 63;
    int l15 = lane & 15, quad = lane >> 4;

    int qrow_base = qt * 128 + w * 32;
    int qb = 1 + f * 1200 + half * 600;
    int kb = 1 + f * 1200 + (1 - half) * 600;

    bf16x8 aQ[2][2];
    #pragma unroll
    for (int mf = 0; mf < 2; mf++) {
        int qr = qrow_base + mf * 16 + l15;
        int qtok = qb + ((qr < 600) ? qr : 0);
        const unsigned short* qp = qkv + (size_t)qtok * QKV_ST + h * 64;
        #pragma unroll
        for (int ks = 0; ks < 2; ks++)
            aQ[mf][ks] = *(const bf16x8*)(qp + ks * 32 + quad * 8);
    }

    f32x4 O[2][4] = {};
    float mrow[2][4], lrow[2][4];
    #pragma unroll
    for (int mf = 0; mf < 2; mf++)
        #pragma unroll
        for (int r = 0; r < 4; r++) { mrow[mf][r] = -1e30f; lrow[mf][r] = 0.f; }

    for (int kt = 0; kt < 10; kt++) {
        __syncthreads();
        #pragma unroll
        for (int it = 0; it < 2; it++) {
            int c = tid + it * 256;
            int row = c >> 3, dc = (c & 7) * 8;
            int kidx = kt * 64 + row;
            int tok = (kidx == 0) ? 0 : ((kidx <= 600) ? kb + kidx - 1 : 0);
            const unsigned short* kp = qkv + (size_t)tok * QKV_ST + 512 + h * 64 + dc;
            *(bf16x8*)&Ksm[row * SPAD + dc] = *(const bf16x8*)kp;
            union { bf16x8 v; unsigned short u[8]; } vv;
            vv.v = *(const bf16x8*)(kp + 512);
            #pragma unroll
            for (int e = 0; e < 8; e++)
                VTsm[(dc + e) * SPAD + row] = vv.u[e];
        }
        __syncthreads();

        f32x4 S[2][4] = {};
        #pragma unroll
        for (int ks = 0; ks < 2; ks++) {
            bf16x8 bK[4];
            #pragma unroll
            for (int nf = 0; nf < 4; nf++)
                bK[nf] = *(const bf16x8*)&Ksm[(nf * 16 + l15) * SPAD + ks * 32 + quad * 8];
            #pragma unroll
            for (int mf = 0; mf < 2; mf++)
                #pragma unroll
                for (int nf = 0; nf < 4; nf++)
                    S[mf][nf] = __builtin_amdgcn_mfma_f32_16x16x32_bf16(
                                    aQ[mf][ks], bK[nf], S[mf][nf], 0, 0, 0);
        }

        #pragma unroll
        for (int mf = 0; mf < 2; mf++) {
            float pv[4][4];
            float lm[4] = {-1e30f, -1e30f, -1e30f, -1e30f};
            #pragma unroll
            for (int nf = 0; nf < 4; nf++) {
                int kidx = kt * 64 + nf * 16 + l15;
                bool valid = kidx <= 600;
                #pragma unroll
                for (int r = 0; r < 4; r++) {
                    float s = valid ? S[mf][nf][r] * 0.125f : -1e30f;
                    pv[nf][r] = s;
                    lm[r] = fmaxf(lm[r], s);
                }
            }
            #pragma unroll
            for (int off = 1; off < 16; off <<= 1)
                #pragma unroll
                for (int r = 0; r < 4; r++)
                    lm[r] = fmaxf(lm[r], __shfl_xor(lm[r], off));
            #pragma unroll
            for (int r = 0; r < 4; r++) {
                float nm = fmaxf(mrow[mf][r], lm[r]);
                float c = __expf(mrow[mf][r] - nm);
                mrow[mf][r] = nm;
                lrow[mf][r] *= c;
                #pragma unroll
                for (int nf = 0; nf < 4; nf++) O[mf][nf][r] *= c;
            }
            float rs[4] = {0.f, 0.f, 0.f, 0.f};
            #pragma unroll
            for (int nf = 0; nf < 4; nf++)
                #pragma unroll
                for (int r = 0; r < 4; r++) {
                    float p = __expf(pv[nf][r] - mrow[mf][r]);
                    pv[nf][r] = p;
                    rs[r] += p;
                }
            #pragma unroll
            for (int off = 1; off < 16; off <<= 1)
                #pragma unroll
                for (int r = 0; r < 4; r++)
                    rs[r] += __shfl_xor(rs[r], off);
            #pragma unroll
            for (int r = 0; r < 4; r++) lrow[mf][r] += rs[r];
            #pragma unroll
            for (int nf = 0; nf < 4; nf++)
                #pragma unroll
                for (int r = 0; r < 4; r++)
                    Psm[w][(mf * 16 + quad * 4 + r) * SPAD + nf * 16 + l15] = (short)f2b(pv[nf][r]);
        }
        asm volatile("s_waitcnt lgkmcnt(0)" ::: "memory");

        #pragma unroll
        for (int ks2 = 0; ks2 < 2; ks2++) {
            bf16x8 aP[2], bV[4];
            #pragma unroll
            for (int mf = 0; mf < 2; mf++)
                aP[mf] = *(const bf16x8*)&Psm[w][(mf * 16 + l15) * SPAD + ks2 * 32 + quad * 8];
            #pragma unroll
            for (int nf = 0; nf < 4; nf++)
                bV[nf] = *(const bf16x8*)&VTsm[(nf * 16 + l15) * SPAD + ks2 * 32 + quad * 8];
            #pragma unroll
            for (int mf = 0; mf < 2; mf++)
                #pragma unroll
                for (int nf = 0; nf < 4; nf++)
                    O[mf][nf] = __builtin_amdgcn_mfma_f32_16x16x32_bf16(
                                    aP[mf], bV[nf], O[mf][nf], 0, 0, 0);
        }
    }

    #pragma unroll
    for (int mf = 0; mf < 2; mf++)
        #pragma unroll
        for (int r = 0; r < 4; r++) {
            int qr = qrow_base + mf * 16 + quad * 4 + r;
            if (qr >= 600) continue;
            int qtok = qb + qr;
            float rl = 1.f / lrow[mf][r];
            #pragma unroll
            for (int nf = 0; nf < 4; nf++)
                out[(size_t)qtok * DM + h * 64 + nf * 16 + l15] = f2b(O[mf][nf][r] * rl);
        }
}

// ------------------------------ cls attention (split-K) --------------------
__global__ __launch_bounds__(256) void cls_attn_part(
    const unsigned short* __restrict__ qkv, float* __restrict__ part)
{
    int ch = blockIdx.x, h = blockIdx.y;
    int wid = threadIdx.x >> 6, lane = threadIdx.x & 63;
    __shared__ float sm[4], sl[4], sa[4][64];
    float qv = b2f(qkv[h * 64 + lane]) * 0.125f;
    int k0 = ch * 100 + wid * 25;
    float m = -1e30f, l = 0.f, acc = 0.f;
    for (int i = 0; i < 25; i += 2) {
        int key0 = k0 + i, key1 = key0 + 1;
        bool ok0 = key0 < NT;
        bool ok1 = (i + 1 < 25) && (key1 < NT);
        const unsigned short* kr0 = qkv + (size_t)(ok0 ? key0 : 0) * QKV_ST + 512 + h * 64;
        const unsigned short* kr1 = qkv + (size_t)(ok1 ? key1 : 0) * QKV_ST + 512 + h * 64;
        float s0 = qv * b2f(kr0[lane]);
        float v0 = b2f(kr0[512 + lane]);
        float s1 = qv * b2f(kr1[lane]);
        float v1 = b2f(kr1[512 + lane]);
        #pragma unroll
        for (int off = 32; off >= 1; off >>= 1) {
            s0 += __shfl_xor(s0, off);
            s1 += __shfl_xor(s1, off);
        }
        float nm = m;
        if (ok0) nm = fmaxf(nm, s0);
        if (ok1) nm = fmaxf(nm, s1);
        float c  = __expf(m - nm);
        float p0 = ok0 ? __expf(s0 - nm) : 0.f;
        float p1 = ok1 ? __expf(s1 - nm) : 0.f;
        l   = l * c + p0 + p1;
        acc = acc * c + p0 * v0 + p1 * v1;
        m = nm;
    }
    if (lane == 0) { sm[wid] = m; sl[wid] = l; }
    sa[wid][lane] = acc;
    __syncthreads();
    if (wid == 0) {
        float M2 = fmaxf(fmaxf(sm[0], sm[1]), fmaxf(sm[2], sm[3]));
        float L = 0.f, o = 0.f;
        #pragma unroll
        for (int w = 0; w < 4; w++) {
            float c = __expf(sm[w] - M2);
            L += sl[w] * c;
            o += sa[w][lane] * c;
        }
        float* p = part + ((size_t)h * NCH + ch) * 68;
        if (lane == 0) { p[0] = M2; p[1] = L; }
        p[4 + lane] = o;
    }
}

__global__ __launch_bounds__(64) void cls_attn_reduce(
    const float* __restrict__ part, unsigned short* __restrict__ out)
{
    int h = blockIdx.x, lane = threadIdx.x;
    float m = -1e30f, l = 0.f, acc = 0.f;
    for (int c = 0; c < NCH; c++) {
        const float* p = part + ((size_t)h * NCH + c) * 68;
        float cm = p[0], cl = p[1], ca = p[4 + lane];
        float nm = fmaxf(m, cm);
        float e1 = __expf(m - nm), e2 = __expf(cm - nm);
        l   = l * e1 + cl * e2;
        acc = acc * e1 + ca * e2;
        m = nm;
    }
    out[h * 64 + lane] = f2b(acc / l);
}

// ------------------------------ head ---------------------------------------
__global__ __launch_bounds__(64) void head_kernel(
    const float* __restrict__ x, const float* __restrict__ g,
    const float* __restrict__ b, const float* __restrict__ w,
    const float* __restrict__ ob, float* __restrict__ out)
{
    __shared__ float xn[DM];
    int lane = threadIdx.x;
    const float4* xr = (const float4*)x;
    float4 v0 = xr[lane * 2], v1 = xr[lane * 2 + 1];
    float s  = v0.x + v0.y + v0.z + v0.w + v1.x + v1.y + v1.z + v1.w;
    float s2 = v0.x*v0.x + v0.y*v0.y + v0.z*v0.z + v0.w*v0.w
             + v1.x*v1.x + v1.y*v1.y + v1.z*v1.z + v1.w*v1.w;
    #pragma unroll
    for (int off = 32; off >= 1; off >>= 1) {
        s  += __shfl_xor(s, off);
        s2 += __shfl_xor(s2, off);
    }
    float mu = s * (1.f / DM);
    float var = s2 * (1.f / DM) - mu * mu;
    float r = rsqrtf(var + LN_EPS);
    #pragma unroll
    for (int i = 0; i < 8; i++) {
        int d = lane * 8 + i;
        xn[d] = (x[d] - mu) * r * g[d] + b[d];
    }
    __syncthreads();
    if (lane < 60) {
        float a = ob[lane];
        for (int d = 0; d < DM; d++) a += xn[d] * w[d * 60 + lane];
        out[lane] = a;
    }
}

// ------------------------------ driver -------------------------------------
extern "C" void kernel_launch(void* const* d_in, const int* in_sizes, int n_in,
                              void* d_out, int out_size, void* d_ws, size_t ws_size,
                              hipStream_t stream)
{
    const float* video     = (const float*)d_in[0];
    const float* patch_w   = (const float*)d_in[1];
    const float* patch_b   = (const float*)d_in[2];
    const float* pos_emb   = (const float*)d_in[3];
    const float* cls_token = (const float*)d_in[4];
    const float* t_ln_g    = (const float*)d_in[5];
    const float* t_ln_b    = (const float*)d_in[6];
    const float* t_qkv_w   = (const float*)d_in[7];
    const float* t_out_w   = (const float*)d_in[8];
    const float* t_out_b   = (const float*)d_in[9];
    const float* s_ln_g    = (const float*)d_in[10];
    const float* s_ln_b    = (const float*)d_in[11];
    const float* s_qkv_w   = (const float*)d_in[12];
    const float* s_out_w   = (const float*)d_in[13];
    const float* s_out_b   = (const float*)d_in[14];
    const float* f_ln_g    = (const float*)d_in[15];
    const float* f_ln_b    = (const float*)d_in[16];
    const float* f_w1      = (const float*)d_in[17];
    const float* f_b1      = (const float*)d_in[18];
    const float* f_w2      = (const float*)d_in[19];
    const float* f_b2      = (const float*)d_in[20];
    const float* o_ln_g    = (const float*)d_in[21];
    const float* o_ln_b    = (const float*)d_in[22];
    const float* o_w       = (const float*)d_in[23];
    const float* o_b       = (const float*)d_in[24];

    char* ws = (char*)d_ws;
    size_t o = 0;
    float*          X    = (float*)(ws + o);          o += (size_t)(MP + 1) * 512 * 4;
    unsigned short* XN   = (unsigned short*)(ws + o); o += (size_t)MP * 512 * 2;
    unsigned short* QKV  = (unsigned short*)(ws + o); o += (size_t)MP * 1536 * 2;
    unsigned short* H16  = (unsigned short*)(ws + o); o += (size_t)MP * 4096 * 2;
    unsigned short* MID  = (unsigned short*)(ws + o); o += (size_t)MP * 2048 * 2;
    unsigned short* PT   = (unsigned short*)(ws + o); o += (size_t)MP * 768 * 2;
    unsigned short* W16  = (unsigned short*)(ws + o); o += (size_t)5242880 * 2;
    unsigned short* PW16 = (unsigned short*)(ws + o); o += (size_t)512 * 768 * 2;
    float*          CP   = (float*)(ws + o);          o += (size_t)8 * NCH * 68 * 4;

    // ---- patch embed + cls + pos ----
    patchify_kernel<<<(NP * 768 + 255) / 256, 256, 0, stream>>>(video, PT);
    cls_init_kernel<<<2, 256, 0, stream>>>(cls_token, pos_emb, X);
    posx_init<<<NP * DM / 4 / 256, 256, 0, stream>>>(pos_emb, X);
    convertT_one<<<(768 / 32) * (512 / 32), 256, 0, stream>>>(patch_w, PW16, 768, 512);
    mfma_gemm_sk<3><<<dim3(4, 38, 3), 256, 0, stream>>>(PT, PW16, patch_b,
                                                        X + DM, NP, DM, 768);

    dim3 g_qkv(12, 38), g_ff1(16, 38);
    dim3 g_out_sk(4, 38, 2), g_ff2_sk(4, 38, 4);
    for (int i = 0; i < 12; i++) {
        convertT_layer<<<5120, 256, 0, stream>>>(
            t_qkv_w + (size_t)i * 512 * 1536, t_out_w + (size_t)i * 512 * 512,
            s_qkv_w + (size_t)i * 512 * 1536, s_out_w + (size_t)i * 512 * 512,
            f_w1 + (size_t)i * 512 * 4096, f_w2 + (size_t)i * 2048 * 512, W16);

        // ---- time attention block ----
        ln_bf16<<<1201, 256, 0, stream>>>(X, t_ln_g + i * DM, t_ln_b + i * DM, XN, NT);
        mfma_gemm<true><<<g_qkv, 256, 0, stream>>>(XN, W16 + 0, nullptr, nullptr,
                                                   QKV, NT, QKV_ST, DM);
        time_attn4<<<600, 256, 0, stream>>>(QKV, MID);
        cls_attn_part<<<dim3(NCH, 8), 256, 0, stream>>>(QKV, CP);
        cls_attn_reduce<<<8, 64, 0, stream>>>(CP, MID);
        mfma_gemm_sk<2><<<g_out_sk, 256, 0, stream>>>(MID, W16 + 786432, t_out_b + i * DM,
                                                      X, NT, DM, DM);
        // ---- space attention block ----
        ln_bf16<<<1201, 256, 0, stream>>>(X, s_ln_g + i * DM, s_ln_b + i * DM, XN, NT);
        mfma_gemm<true><<<g_qkv, 256, 0, stream>>>(XN, W16 + 1048576, nullptr, nullptr,
                                                   QKV, NT, QKV_ST, DM);
        space_attn_mfma<<<dim3(5, 8, 8), 256, 0, stream>>>(QKV, MID);
        cls_attn_part<<<dim3(NCH, 8), 256, 0, stream>>>(QKV, CP);
        cls_attn_reduce<<<8, 64, 0, stream>>>(CP, MID);
        mfma_gemm_sk<2><<<g_out_sk, 256, 0, stream>>>(MID, W16 + 1835008, s_out_b + i * DM,
                                                      X, NT, DM, DM);
        // ---- GeGLU FF block (FF1 fused with GeGLU -> MID) ----
        ln_bf16<<<1201, 256, 0, stream>>>(X, f_ln_g + i * DM, f_ln_b + i * DM, XN, NT);
        mfma_ff1_geglu<<<g_ff1, 256, 0, stream>>>(XN, W16 + 2097152, f_b1 + i * 4096,
                                                  MID, NT);
        mfma_gemm_sk<4><<<g_ff2_sk, 256, 0, stream>>>(MID, W16 + 4194304, f_b2 + i * DM,
                                                      X, NT, DM, 2048);
    }

    head_kernel<<<1, 64, 0, stream>>>(X, o_ln_g, o_ln_b, o_w, o_b, (float*)d_out);
}

// Round 5
// 4378.297 us; speedup vs baseline: 1.3706x; 1.0010x over previous
//
#include <hip/hip_runtime.h>
#include <cmath>

// ---------------------------------------------------------------------------
// MutualTimeSformer — round 8: R4 + (a) split-K-aware XCD remap: all z-splits
// of an output tile on ONE XCD so fp32 atomics coalesce in its L2 (R4's remap
// scattered them -> WRITE 9.6->38.4MB, +17us/dispatch), (b) FF1+GeGLU gets the
// counted-vmcnt double-buffer (was full-drain __syncthreads per k-iter).
// Dims: B=1, F=4, n=1200/frame, N=4801 tokens (pad 4864), D=512, H=8, DH=64
// ---------------------------------------------------------------------------

#define NT      4801
#define NP      4800
#define MP      4864          // padded row count (38 * 128)
#define DM      512
#define QKV_ST  1536
#define LN_EPS  1e-5f
#define NCH     49            // cls split-K chunks (49*100 >= 4801)

typedef __attribute__((ext_vector_type(8))) short bf16x8;
typedef __attribute__((ext_vector_type(4))) float f32x4;

__device__ __forceinline__ unsigned short f2b(float f) {
    union { float f; unsigned int u; } x; x.f = f;
    unsigned int r = (x.u + 0x7FFFu + ((x.u >> 16) & 1u)) >> 16;
    return (unsigned short)r;
}
__device__ __forceinline__ float b2f(unsigned short b) {
    union { unsigned int u; float f; } x; x.u = ((unsigned int)b) << 16;
    return x.f;
}
__device__ __forceinline__ unsigned int pack2(float a, float b) {
    return (unsigned int)f2b(a) | ((unsigned int)f2b(b) << 16);
}

__device__ __forceinline__ void gl_lds16(const void* g, void* l) {
    __builtin_amdgcn_global_load_lds(
        (__attribute__((address_space(1))) unsigned int*)(unsigned long long)(uintptr_t)g,
        (__attribute__((address_space(3))) unsigned int*)l, 16, 0, 0);
}

// bijective XCD-chunk remap for 2D grids (nwg % 8 == 0 for all users):
// consecutive logical ids (x fastest) land on one XCD -> shared A row-panels.
__device__ __forceinline__ void xcd_remap(int& bx, int& by, int& bz) {
    const int gx = gridDim.x, gy = gridDim.y;
    const int nwg = gx * gy * gridDim.z;
    const int orig = (blockIdx.z * gy + blockIdx.y) * gx + blockIdx.x;
    const int q = nwg >> 3, r = nwg & 7;
    const int xcd = orig & 7, idx = orig >> 3;
    const int id = (xcd < r ? xcd * (q + 1) : r * (q + 1) + (xcd - r) * q) + idx;
    bx = id % gx;
    const int t = id / gx;
    by = t % gy;
    bz = t / gy;
}

// split-K-aware remap: hw XCD = linear%8. XCD c's k-th slot -> tile
// t = c*tpx + k%tpx, split bz = k/tpx. All splits of tile t share c = t/tpx
// -> atomics to that tile coalesce in one XCD's L2. Requires gx*gy % 8 == 0.
__device__ __forceinline__ void xcd_remap_sk(int& bx, int& by, int& bz) {
    const int gx = gridDim.x, gy = gridDim.y;
    const int tpx = (gx * gy) >> 3;          // tiles per XCD
    const int L = (blockIdx.z * gy + blockIdx.y) * gx + blockIdx.x;
    const int c = L & 7, k = L >> 3;
    bz = k / tpx;
    const int t = c * tpx + (k - bz * tpx);
    bx = t % gx;
    by = t / gx;
}

// ------------------------------ patchify (fp32 -> bf16) --------------------
__global__ void patchify_kernel(const float* __restrict__ video, unsigned short* __restrict__ out)
{
    int idx = blockIdx.x * 256 + threadIdx.x;
    if (idx >= NP * 768) return;
    int tok = idx / 768, e = idx % 768;
    int c  = e % 3;
    int pe = e / 3;
    int p2 = pe % 16, p1 = pe / 16;
    int half = tok / 2400, r = tok % 2400;
    int f = r / 600, rr = r % 600;
    int hi = rr / 20, wi = rr % 20;
    int row = hi * 16 + p1;
    int col = half * 320 + wi * 16 + p2;
    out[idx] = f2b(video[(((size_t)f * 3 + c) * 480 + row) * 640 + col]);
}

__global__ void cls_init_kernel(const float* __restrict__ cls_token,
                                const float* __restrict__ pos, float* __restrict__ X)
{
    int d = blockIdx.x * 256 + threadIdx.x;
    if (d < DM) X[d] = cls_token[d] + pos[d];
}

// pre-init X rows 1..4800 with pos_emb (patch GEMM atomically accumulates)
__global__ void posx_init(const float* __restrict__ pos, float* __restrict__ X)
{
    int i = blockIdx.x * 256 + threadIdx.x;
    if (i < NP * DM / 4)
        ((float4*)(X + DM))[i] = ((const float4*)(pos + DM))[i];
}

// ------------------------------ weight transpose-convert -------------------
__device__ __forceinline__ void transpose_tile(const float* __restrict__ in,
                                               unsigned short* __restrict__ out,
                                               int K, int N, int tile)
{
    __shared__ float T[32][33];
    int ntk = K / 32;
    int kt = tile % ntk, nt = tile / ntk;
    int k0 = kt * 32, n0 = nt * 32;
    int tx = threadIdx.x & 31, ty = threadIdx.x >> 5;
    #pragma unroll
    for (int i = 0; i < 4; i++)
        T[ty + 8 * i][tx] = in[(size_t)(k0 + ty + 8 * i) * N + n0 + tx];
    __syncthreads();
    #pragma unroll
    for (int i = 0; i < 4; i++)
        out[(size_t)(n0 + ty + 8 * i) * K + k0 + tx] = f2b(T[tx][ty + 8 * i]);
}

__global__ __launch_bounds__(256) void convertT_layer(
    const float* __restrict__ w0, const float* __restrict__ w1,
    const float* __restrict__ w2, const float* __restrict__ w3,
    const float* __restrict__ w4, const float* __restrict__ w5,
    unsigned short* __restrict__ out)
{
    int t = blockIdx.x;
    if      (t <  768) transpose_tile(w0, out + 0,       512, 1536, t);
    else if (t < 1024) transpose_tile(w1, out + 786432,  512,  512, t - 768);
    else if (t < 1792) transpose_tile(w2, out + 1048576, 512, 1536, t - 1024);
    else if (t < 2048) transpose_tile(w3, out + 1835008, 512,  512, t - 1792);
    else if (t < 4096) transpose_tile(w4, out + 2097152, 512, 4096, t - 2048);
    else               transpose_tile(w5, out + 4194304, 2048, 512, t - 4096);
}

__global__ __launch_bounds__(256) void convertT_one(
    const float* __restrict__ in, unsigned short* __restrict__ out, int K, int N)
{
    transpose_tile(in, out, K, N, blockIdx.x);
}

// -------------------- MFMA GEMM (128x128, counted-vmcnt dbuf) --------------
template<bool OB16>
__global__ __launch_bounds__(256, 2) void mfma_gemm(
    const unsigned short* __restrict__ A, const unsigned short* __restrict__ BT,
    const float* __restrict__ bias, const float* __restrict__ add,
    void* __restrict__ C, int Mv, int N, int K)
{
    __shared__ short Asm[2][128 * 64];
    __shared__ short Bsm[2][128 * 64];
    int bx, by, bz; xcd_remap(bx, by, bz); (void)bz;
    const int tid = threadIdx.x, w = tid >> 6, lane = tid & 63;
    const int row0 = by * 128, col0 = bx * 128;
    const int wm = w >> 1, wn = w & 1;
    const int l15 = lane & 15, quad = lane >> 4;

    f32x4 acc[4][4] = {};

    int ar[4], aq[4];
    #pragma unroll
    for (int i = 0; i < 4; i++) {
        int c = (w * 4 + i) * 64 + lane;
        ar[i] = c >> 3;
        aq[i] = (c & 7) ^ ((c >> 3) & 7);
    }
    const unsigned short* Ab = A  + (size_t)row0 * K;
    const unsigned short* Bb = BT + (size_t)col0 * K;

    // prologue: stage k-tile 0 into buffer 0 (8 vm ops/thread)
    #pragma unroll
    for (int i = 0; i < 4; i++) {
        gl_lds16(Ab + (size_t)ar[i] * K + aq[i] * 8, &Asm[0][(w * 4 + i) * 512]);
        gl_lds16(Bb + (size_t)ar[i] * K + aq[i] * 8, &Bsm[0][(w * 4 + i) * 512]);
    }

    const int nt = K >> 6;
    int cur = 0;
    for (int t = 0; t < nt; t++) {
        if (t + 1 < nt) {
            const int k0 = (t + 1) << 6;
            #pragma unroll
            for (int i = 0; i < 4; i++) {
                gl_lds16(Ab + (size_t)ar[i] * K + k0 + aq[i] * 8,
                         &Asm[cur ^ 1][(w * 4 + i) * 512]);
                gl_lds16(Bb + (size_t)ar[i] * K + k0 + aq[i] * 8,
                         &Bsm[cur ^ 1][(w * 4 + i) * 512]);
            }
            // wait only for tile t (the 8 newest ops stay in flight)
            asm volatile("s_waitcnt vmcnt(8)\ns_barrier" ::: "memory");
        } else {
            asm volatile("s_waitcnt vmcnt(0)\ns_barrier" ::: "memory");
        }
        const short* As = Asm[cur];
        const short* Bs = Bsm[cur];
        #pragma unroll
        for (int ks = 0; ks < 2; ks++) {
            bf16x8 af[4], bfr[4];
            #pragma unroll
            for (int i = 0; i < 4; i++) {
                int m  = wm * 64 + i * 16 + l15;
                af[i]  = *(const bf16x8*)&As[m * 64 + (((ks * 4 + quad) ^ (m & 7))) * 8];
                int n  = wn * 64 + i * 16 + l15;
                bfr[i] = *(const bf16x8*)&Bs[n * 64 + (((ks * 4 + quad) ^ (n & 7))) * 8];
            }
            #pragma unroll
            for (int i = 0; i < 4; i++)
                #pragma unroll
                for (int j = 0; j < 4; j++)
                    acc[i][j] = __builtin_amdgcn_mfma_f32_16x16x32_bf16(
                                    af[i], bfr[j], acc[i][j], 0, 0, 0);
        }
        asm volatile("s_barrier" ::: "memory");  // protect buf before next stage
        cur ^= 1;
    }

    #pragma unroll
    for (int i = 0; i < 4; i++) {
        #pragma unroll
        for (int r = 0; r < 4; r++) {
            int row = row0 + wm * 64 + i * 16 + quad * 4 + r;
            if (row >= Mv) continue;
            #pragma unroll
            for (int j = 0; j < 4; j++) {
                int col = col0 + wn * 64 + j * 16 + l15;
                float v = acc[i][j][r];
                if (bias) v += bias[col];
                if (add)  v += add[(size_t)row * N + col];
                if (OB16) ((unsigned short*)C)[(size_t)row * N + col] = f2b(v);
                else      ((float*)C)[(size_t)row * N + col] = v;
            }
        }
    }
}

// ------------- split-K MFMA GEMM (fp32 atomics, counted-vmcnt dbuf) --------
// C pre-initialized with the additive term. bias added by kz==0 split only.
template<int SPLITS>
__global__ __launch_bounds__(256, 2) void mfma_gemm_sk(
    const unsigned short* __restrict__ A, const unsigned short* __restrict__ BT,
    const float* __restrict__ bias, float* __restrict__ C, int Mv, int N, int K)
{
    __shared__ short Asm[2][128 * 64];
    __shared__ short Bsm[2][128 * 64];
    int bx, by, bz; xcd_remap_sk(bx, by, bz);
    const int tid = threadIdx.x, w = tid >> 6, lane = tid & 63;
    const int row0 = by * 128, col0 = bx * 128;
    const int wm = w >> 1, wn = w & 1;
    const int l15 = lane & 15, quad = lane >> 4;
    const int kchunk = K / SPLITS;
    const int kbeg = bz * kchunk;

    f32x4 acc[4][4] = {};

    int ar[4], aq[4];
    #pragma unroll
    for (int i = 0; i < 4; i++) {
        int c = (w * 4 + i) * 64 + lane;
        ar[i] = c >> 3;
        aq[i] = (c & 7) ^ ((c >> 3) & 7);
    }
    const unsigned short* Ab = A  + (size_t)row0 * K + kbeg;
    const unsigned short* Bb = BT + (size_t)col0 * K + kbeg;

    #pragma unroll
    for (int i = 0; i < 4; i++) {
        gl_lds16(Ab + (size_t)ar[i] * K + aq[i] * 8, &Asm[0][(w * 4 + i) * 512]);
        gl_lds16(Bb + (size_t)ar[i] * K + aq[i] * 8, &Bsm[0][(w * 4 + i) * 512]);
    }

    const int nt = kchunk >> 6;
    int cur = 0;
    for (int t = 0; t < nt; t++) {
        if (t + 1 < nt) {
            const int k0 = (t + 1) << 6;
            #pragma unroll
            for (int i = 0; i < 4; i++) {
                gl_lds16(Ab + (size_t)ar[i] * K + k0 + aq[i] * 8,
                         &Asm[cur ^ 1][(w * 4 + i) * 512]);
                gl_lds16(Bb + (size_t)ar[i] * K + k0 + aq[i] * 8,
                         &Bsm[cur ^ 1][(w * 4 + i) * 512]);
            }
            asm volatile("s_waitcnt vmcnt(8)\ns_barrier" ::: "memory");
        } else {
            asm volatile("s_waitcnt vmcnt(0)\ns_barrier" ::: "memory");
        }
        const short* As = Asm[cur];
        const short* Bs = Bsm[cur];
        #pragma unroll
        for (int ks = 0; ks < 2; ks++) {
            bf16x8 af[4], bfr[4];
            #pragma unroll
            for (int i = 0; i < 4; i++) {
                int m  = wm * 64 + i * 16 + l15;
                af[i]  = *(const bf16x8*)&As[m * 64 + (((ks * 4 + quad) ^ (m & 7))) * 8];
                int n  = wn * 64 + i * 16 + l15;
                bfr[i] = *(const bf16x8*)&Bs[n * 64 + (((ks * 4 + quad) ^ (n & 7))) * 8];
            }
            #pragma unroll
            for (int i = 0; i < 4; i++)
                #pragma unroll
                for (int j = 0; j < 4; j++)
                    acc[i][j] = __builtin_amdgcn_mfma_f32_16x16x32_bf16(
                                    af[i], bfr[j], acc[i][j], 0, 0, 0);
        }
        asm volatile("s_barrier" ::: "memory");
        cur ^= 1;
    }

    const bool addb = (bz == 0) && (bias != nullptr);
    #pragma unroll
    for (int i = 0; i < 4; i++) {
        #pragma unroll
        for (int r = 0; r < 4; r++) {
            int row = row0 + wm * 64 + i * 16 + quad * 4 + r;
            if (row >= Mv) continue;
            #pragma unroll
            for (int j = 0; j < 4; j++) {
                int col = col0 + wn * 64 + j * 16 + l15;
                float v = acc[i][j][r];
                if (addb) v += bias[col];
                unsafeAtomicAdd(&C[(size_t)row * N + col], v);
            }
        }
    }
}

// -------------- FF1 + GeGLU fused (u-tile and g-tile per block) ------------
// A: XN [MP,512] bf16; BT: [4096,512] bf16 (row = output col). Block (bx,by)
// computes rows by*128, u-cols bx*128 and g-cols bx*128+2048, writes
// geglu(u,g) bf16 directly to out[row*2048 + ucol]. Grid (16, 38).
// Counted-vmcnt dbuf: 96KB LDS -> 1 block/CU; nt=8 gives pipeline depth.
__global__ __launch_bounds__(256, 1) void mfma_ff1_geglu(
    const unsigned short* __restrict__ A, const unsigned short* __restrict__ BT,
    const float* __restrict__ b1, unsigned short* __restrict__ out, int Mv)
{
    __shared__ short Asm[2][128 * 64];
    __shared__ short Bu[2][128 * 64];
    __shared__ short Bg[2][128 * 64];
    int bx, by, bz; xcd_remap(bx, by, bz); (void)bz;
    const int tid = threadIdx.x, w = tid >> 6, lane = tid & 63;
    const int row0 = by * 128, colu0 = bx * 128;
    const int wm = w >> 1, wn = w & 1;
    const int l15 = lane & 15, quad = lane >> 4;

    f32x4 au[4][4] = {};
    f32x4 ag[4][4] = {};

    int ar[4], aq[4];
    #pragma unroll
    for (int i = 0; i < 4; i++) {
        int c = (w * 4 + i) * 64 + lane;
        ar[i] = c >> 3;
        aq[i] = (c & 7) ^ ((c >> 3) & 7);
    }
    const unsigned short* Ab  = A  + (size_t)row0 * 512;
    const unsigned short* Bub = BT + (size_t)colu0 * 512;
    const unsigned short* Bgb = BT + (size_t)(colu0 + 2048) * 512;

    // prologue: k-tile 0 into buffer 0 (12 vm ops/thread)
    #pragma unroll
    for (int i = 0; i < 4; i++) {
        gl_lds16(Ab  + (size_t)ar[i] * 512 + aq[i] * 8, &Asm[0][(w * 4 + i) * 512]);
        gl_lds16(Bub + (size_t)ar[i] * 512 + aq[i] * 8, &Bu[0][(w * 4 + i) * 512]);
        gl_lds16(Bgb + (size_t)ar[i] * 512 + aq[i] * 8, &Bg[0][(w * 4 + i) * 512]);
    }

    int cur = 0;
    for (int t = 0; t < 8; t++) {
        if (t + 1 < 8) {
            const int k0 = (t + 1) << 6;
            #pragma unroll
            for (int i = 0; i < 4; i++) {
                gl_lds16(Ab  + (size_t)ar[i] * 512 + k0 + aq[i] * 8,
                         &Asm[cur ^ 1][(w * 4 + i) * 512]);
                gl_lds16(Bub + (size_t)ar[i] * 512 + k0 + aq[i] * 8,
                         &Bu[cur ^ 1][(w * 4 + i) * 512]);
                gl_lds16(Bgb + (size_t)ar[i] * 512 + k0 + aq[i] * 8,
                         &Bg[cur ^ 1][(w * 4 + i) * 512]);
            }
            asm volatile("s_waitcnt vmcnt(12)\ns_barrier" ::: "memory");
        } else {
            asm volatile("s_waitcnt vmcnt(0)\ns_barrier" ::: "memory");
        }
        const short* As = Asm[cur];
        const short* Bus = Bu[cur];
        const short* Bgs = Bg[cur];
        #pragma unroll
        for (int ks = 0; ks < 2; ks++) {
            bf16x8 af[4], bu[4], bg[4];
            #pragma unroll
            for (int i = 0; i < 4; i++) {
                int m = wm * 64 + i * 16 + l15;
                int p = (((ks * 4 + quad) ^ (m & 7))) * 8;
                af[i] = *(const bf16x8*)&As[m * 64 + p];
                int n = wn * 64 + i * 16 + l15;
                int pb = (((ks * 4 + quad) ^ (n & 7))) * 8;
                bu[i] = *(const bf16x8*)&Bus[n * 64 + pb];
                bg[i] = *(const bf16x8*)&Bgs[n * 64 + pb];
            }
            #pragma unroll
            for (int i = 0; i < 4; i++)
                #pragma unroll
                for (int j = 0; j < 4; j++) {
                    au[i][j] = __builtin_amdgcn_mfma_f32_16x16x32_bf16(
                                   af[i], bu[j], au[i][j], 0, 0, 0);
                    ag[i][j] = __builtin_amdgcn_mfma_f32_16x16x32_bf16(
                                   af[i], bg[j], ag[i][j], 0, 0, 0);
                }
        }
        asm volatile("s_barrier" ::: "memory");
        cur ^= 1;
    }

    #pragma unroll
    for (int i = 0; i < 4; i++) {
        #pragma unroll
        for (int r = 0; r < 4; r++) {
            int row = row0 + wm * 64 + i * 16 + quad * 4 + r;
            if (row >= Mv) continue;
            #pragma unroll
            for (int j = 0; j < 4; j++) {
                int col = colu0 + wn * 64 + j * 16 + l15;
                float u = au[i][j][r] + b1[col];
                float g = ag[i][j][r] + b1[col + 2048];
                float h = u * 0.5f * g * (1.f + erff(g * 0.70710678f));
                out[(size_t)row * 2048 + col] = f2b(h);
            }
        }
    }
}

// ------------------------------ LayerNorm (fp32 in, bf16 out) --------------
__global__ __launch_bounds__(256) void ln_bf16(
    const float* __restrict__ x, const float* __restrict__ g,
    const float* __restrict__ b, unsigned short* __restrict__ y, int M)
{
    int wid = threadIdx.x >> 6, lane = threadIdx.x & 63;
    int row = blockIdx.x * 4 + wid;
    if (row >= M) return;
    const float4* xr = (const float4*)(x + (size_t)row * DM);
    float4 v0 = xr[lane * 2], v1 = xr[lane * 2 + 1];
    float s  = v0.x + v0.y + v0.z + v0.w + v1.x + v1.y + v1.z + v1.w;
    float s2 = v0.x*v0.x + v0.y*v0.y + v0.z*v0.z + v0.w*v0.w
             + v1.x*v1.x + v1.y*v1.y + v1.z*v1.z + v1.w*v1.w;
    #pragma unroll
    for (int off = 32; off >= 1; off >>= 1) {
        s  += __shfl_xor(s, off);
        s2 += __shfl_xor(s2, off);
    }
    float mu = s * (1.f / DM);
    float var = s2 * (1.f / DM) - mu * mu;
    float r = rsqrtf(var + LN_EPS);
    const float4* gv = (const float4*)g;
    const float4* bv = (const float4*)b;
    unsigned int* yr = (unsigned int*)(y + (size_t)row * DM);
    #pragma unroll
    for (int i = 0; i < 2; i++) {
        float4 v = (i == 0) ? v0 : v1;
        float4 gg = gv[lane * 2 + i], bb = bv[lane * 2 + i];
        float ox = (v.x - mu) * r * gg.x + bb.x;
        float oy = (v.y - mu) * r * gg.y + bb.y;
        float oz = (v.z - mu) * r * gg.z + bb.z;
        float ow = (v.w - mu) * r * gg.w + bb.w;
        yr[lane * 4 + i * 2 + 0] = pack2(ox, oy);
        yr[lane * 4 + i * 2 + 1] = pack2(oz, ow);
    }
}

// ---------------- time attention (4-way d-split, 600 blocks) ---------------
__global__ __launch_bounds__(256, 4) void time_attn4(
    const unsigned short* __restrict__ qkv, unsigned short* __restrict__ out)
{
    int tid = threadIdx.x;
    int dq = tid & 3, tl = tid >> 2;
    int b = blockIdx.x;
    int h = b / 75;
    int j = (b - h * 75) * 64 + tl;          // 0..4799
    int pos = j % 1200;
    int d0 = dq * 16;
    union { bf16x8 v; unsigned short u[8]; } ld;
    float q[16];
    const unsigned short* qp = qkv + (size_t)(j + 1) * QKV_ST + h * 64 + d0;
    #pragma unroll
    for (int c = 0; c < 2; c++) {
        ld.v = *(const bf16x8*)(qp + c * 8);
        #pragma unroll
        for (int e = 0; e < 8; e++) q[c * 8 + e] = b2f(ld.u[e]) * 0.125f;
    }
    int rows[5] = {0, pos + 1, pos + 1201, pos + 2401, pos + 3601};
    float s[5];
    #pragma unroll
    for (int kk = 0; kk < 5; kk++) {
        const unsigned short* kp = qkv + (size_t)rows[kk] * QKV_ST + 512 + h * 64 + d0;
        float ss = 0.f;
        #pragma unroll
        for (int c = 0; c < 2; c++) {
            ld.v = *(const bf16x8*)(kp + c * 8);
            #pragma unroll
            for (int e = 0; e < 8; e++) ss += q[c * 8 + e] * b2f(ld.u[e]);
        }
        ss += __shfl_xor(ss, 1);
        ss += __shfl_xor(ss, 2);
        s[kk] = ss;
    }
    float mx = s[0];
    #pragma unroll
    for (int kk = 1; kk < 5; kk++) mx = fmaxf(mx, s[kk]);
    float e5[5], l = 0.f;
    #pragma unroll
    for (int kk = 0; kk < 5; kk++) { e5[kk] = __expf(s[kk] - mx); l += e5[kk]; }
    float rl = 1.f / l;
    float acc[16];
    #pragma unroll
    for (int d = 0; d < 16; d++) acc[d] = 0.f;
    #pragma unroll
    for (int kk = 0; kk < 5; kk++) {
        float p = e5[kk] * rl;
        const unsigned short* vp = qkv + (size_t)rows[kk] * QKV_ST + 1024 + h * 64 + d0;
        #pragma unroll
        for (int c = 0; c < 2; c++) {
            ld.v = *(const bf16x8*)(vp + c * 8);
            #pragma unroll
            for (int e = 0; e < 8; e++) acc[c * 8 + e] += p * b2f(ld.u[e]);
        }
    }
    unsigned int* op = (unsigned int*)(out + (size_t)(j + 1) * DM + h * 64 + d0);
    #pragma unroll
    for (int d2 = 0; d2 < 8; d2++) op[d2] = pack2(acc[2 * d2], acc[2 * d2 + 1]);
}

// ------------------------------ space attention (MFMA flash) ----------------
#define SPAD 72
__global__ __launch_bounds__(256, 2) void space_attn_mfma(
    const unsigned short* __restrict__ qkv, unsigned short* __restrict__ out)
{
    __shared__ short Ksm[64 * SPAD];
    __shared__ short VTsm[64 * SPAD];
    __shared__ short Psm[4][32 * SPAD];
    int qt = blockIdx.x, h = blockIdx.y, g = blockIdx.z;
    int f = g >> 1, half = g & 1;
    int tid = threadIdx.x, w = tid >> 6, lane = tid & 63;
    int l15 = lane & 15, quad = lane >> 4;

    int qrow_base = qt * 128 + w * 32;
    int qb = 1 + f * 1200 + half * 600;
    int kb = 1 + f * 1200 + (1 - half) * 600;

    bf16x8 aQ[2][2];
    #pragma unroll
    for (int mf = 0; mf < 2; mf++) {
        int qr = qrow_base + mf * 16 + l15;
        int qtok = qb + ((qr < 600) ? qr : 0);
        const unsigned short* qp = qkv + (size_t)qtok * QKV_ST + h * 64;
        #pragma unroll
        for (int ks = 0; ks < 2; ks++)
            aQ[mf][ks] = *(const bf16x8*)(qp + ks * 32 + quad * 8);
    }

    f32x4 O[2][4] = {};
    float mrow[2][4], lrow[2][4];
    #pragma unroll
    for (int mf = 0; mf < 2; mf++)
        #pragma unroll
        for (int r = 0; r < 4; r++) { mrow[mf][r] = -1e30f; lrow[mf][r] = 0.f; }

    for (int kt = 0; kt < 10; kt++) {
        __syncthreads();
        #pragma unroll
        for (int it = 0; it < 2; it++) {
            int c = tid + it * 256;
            int row = c >> 3, dc = (c & 7) * 8;
            int kidx = kt * 64 + row;
            int tok = (kidx == 0) ? 0 : ((kidx <= 600) ? kb + kidx - 1 : 0);
            const unsigned short* kp = qkv + (size_t)tok * QKV_ST + 512 + h * 64 + dc;
            *(bf16x8*)&Ksm[row * SPAD + dc] = *(const bf16x8*)kp;
            union { bf16x8 v; unsigned short u[8]; } vv;
            vv.v = *(const bf16x8*)(kp + 512);
            #pragma unroll
            for (int e = 0; e < 8; e++)
                VTsm[(dc + e) * SPAD + row] = vv.u[e];
        }
        __syncthreads();

        f32x4 S[2][4] = {};
        #pragma unroll
        for (int ks = 0; ks < 2; ks++) {
            bf16x8 bK[4];
            #pragma unroll
            for (int nf = 0; nf < 4; nf++)
                bK[nf] = *(const bf16x8*)&Ksm[(nf * 16 + l15) * SPAD + ks * 32 + quad * 8];
            #pragma unroll
            for (int mf = 0; mf < 2; mf++)
                #pragma unroll
                for (int nf = 0; nf < 4; nf++)
                    S[mf][nf] = __builtin_amdgcn_mfma_f32_16x16x32_bf16(
                                    aQ[mf][ks], bK[nf], S[mf][nf], 0, 0, 0);
        }

        #pragma unroll
        for (int mf = 0; mf < 2; mf++) {
            float pv[4][4];
            float lm[4] = {-1e30f, -1e30f, -1e30f, -1e30f};
            #pragma unroll
            for (int nf = 0; nf < 4; nf++) {
                int kidx = kt * 64 + nf * 16 + l15;
                bool valid = kidx <= 600;
                #pragma unroll
                for (int r = 0; r < 4; r++) {
                    float s = valid ? S[mf][nf][r] * 0.125f : -1e30f;
                    pv[nf][r] = s;
                    lm[r] = fmaxf(lm[r], s);
                }
            }
            #pragma unroll
            for (int off = 1; off < 16; off <<= 1)
                #pragma unroll
                for (int r = 0; r < 4; r++)
                    lm[r] = fmaxf(lm[r], __shfl_xor(lm[r], off));
            #pragma unroll
            for (int r = 0; r < 4; r++) {
                float nm = fmaxf(mrow[mf][r], lm[r]);
                float c = __expf(mrow[mf][r] - nm);
                mrow[mf][r] = nm;
                lrow[mf][r] *= c;
                #pragma unroll
                for (int nf = 0; nf < 4; nf++) O[mf][nf][r] *= c;
            }
            float rs[4] = {0.f, 0.f, 0.f, 0.f};
            #pragma unroll
            for (int nf = 0; nf < 4; nf++)
                #pragma unroll
                for (int r = 0; r < 4; r++) {
                    float p = __expf(pv[nf][r] - mrow[mf][r]);
                    pv[nf][r] = p;
                    rs[r] += p;
                }
            #pragma unroll
            for (int off = 1; off < 16; off <<= 1)
                #pragma unroll
                for (int r = 0; r < 4; r++)
                    rs[r] += __shfl_xor(rs[r], off);
            #pragma unroll
            for (int r = 0; r < 4; r++) lrow[mf][r] += rs[r];
            #pragma unroll
            for (int nf = 0; nf < 4; nf++)
                #pragma unroll
                for (int r = 0; r < 4; r++)
                    Psm[w][(mf * 16 + quad * 4 + r) * SPAD + nf * 16 + l15] = (short)f2b(pv[nf][r]);
        }
        asm volatile("s_waitcnt lgkmcnt(0)" ::: "memory");

        #pragma unroll
        for (int ks2 = 0; ks2 < 2; ks2++) {
            bf16x8 aP[2], bV[4];
            #pragma unroll
            for (int mf = 0; mf < 2; mf++)
                aP[mf] = *(const bf16x8*)&Psm[w][(mf * 16 + l15) * SPAD + ks2 * 32 + quad * 8];
            #pragma unroll
            for (int nf = 0; nf < 4; nf++)
                bV[nf] = *(const bf16x8*)&VTsm[(nf * 16 + l15) * SPAD + ks2 * 32 + quad * 8];
            #pragma unroll
            for (int mf = 0; mf < 2; mf++)
                #pragma unroll
                for (int nf = 0; nf < 4; nf++)
                    O[mf][nf] = __builtin_amdgcn_mfma_f32_16x16x32_bf16(
                                    aP[mf], bV[nf], O[mf][nf], 0, 0, 0);
        }
    }

    #pragma unroll
    for (int mf = 0; mf < 2; mf++)
        #pragma unroll
        for (int r = 0; r < 4; r++) {
            int qr = qrow_base + mf * 16 + quad * 4 + r;
            if (qr >= 600) continue;
            int qtok = qb + qr;
            float rl = 1.f / lrow[mf][r];
            #pragma unroll
            for (int nf = 0; nf < 4; nf++)
                out[(size_t)qtok * DM + h * 64 + nf * 16 + l15] = f2b(O[mf][nf][r] * rl);
        }
}

// ------------------------------ cls attention (split-K) --------------------
__global__ __launch_bounds__(256) void cls_attn_part(
    const unsigned short* __restrict__ qkv, float* __restrict__ part)
{
    int ch = blockIdx.x, h = blockIdx.y;
    int wid = threadIdx.x >> 6, lane = threadIdx.x & 63;
    __shared__ float sm[4], sl[4], sa[4][64];
    float qv = b2f(qkv[h * 64 + lane]) * 0.125f;
    int k0 = ch * 100 + wid * 25;
    float m = -1e30f, l = 0.f, acc = 0.f;
    for (int i = 0; i < 25; i += 2) {
        int key0 = k0 + i, key1 = key0 + 1;
        bool ok0 = key0 < NT;
        bool ok1 = (i + 1 < 25) && (key1 < NT);
        const unsigned short* kr0 = qkv + (size_t)(ok0 ? key0 : 0) * QKV_ST + 512 + h * 64;
        const unsigned short* kr1 = qkv + (size_t)(ok1 ? key1 : 0) * QKV_ST + 512 + h * 64;
        float s0 = qv * b2f(kr0[lane]);
        float v0 = b2f(kr0[512 + lane]);
        float s1 = qv * b2f(kr1[lane]);
        float v1 = b2f(kr1[512 + lane]);
        #pragma unroll
        for (int off = 32; off >= 1; off >>= 1) {
            s0 += __shfl_xor(s0, off);
            s1 += __shfl_xor(s1, off);
        }
        float nm = m;
        if (ok0) nm = fmaxf(nm, s0);
        if (ok1) nm = fmaxf(nm, s1);
        float c  = __expf(m - nm);
        float p0 = ok0 ? __expf(s0 - nm) : 0.f;
        float p1 = ok1 ? __expf(s1 - nm) : 0.f;
        l   = l * c + p0 + p1;
        acc = acc * c + p0 * v0 + p1 * v1;
        m = nm;
    }
    if (lane == 0) { sm[wid] = m; sl[wid] = l; }
    sa[wid][lane] = acc;
    __syncthreads();
    if (wid == 0) {
        float M2 = fmaxf(fmaxf(sm[0], sm[1]), fmaxf(sm[2], sm[3]));
        float L = 0.f, o = 0.f;
        #pragma unroll
        for (int w = 0; w < 4; w++) {
            float c = __expf(sm[w] - M2);
            L += sl[w] * c;
            o += sa[w][lane] * c;
        }
        float* p = part + ((size_t)h * NCH + ch) * 68;
        if (lane == 0) { p[0] = M2; p[1] = L; }
        p[4 + lane] = o;
    }
}

__global__ __launch_bounds__(64) void cls_attn_reduce(
    const float* __restrict__ part, unsigned short* __restrict__ out)
{
    int h = blockIdx.x, lane = threadIdx.x;
    float m = -1e30f, l = 0.f, acc = 0.f;
    for (int c = 0; c < NCH; c++) {
        const float* p = part + ((size_t)h * NCH + c) * 68;
        float cm = p[0], cl = p[1], ca = p[4 + lane];
        float nm = fmaxf(m, cm);
        float e1 = __expf(m - nm), e2 = __expf(cm - nm);
        l   = l * e1 + cl * e2;
        acc = acc * e1 + ca * e2;
        m = nm;
    }
    out[h * 64 + lane] = f2b(acc / l);
}

// ------------------------------ head ---------------------------------------
__global__ __launch_bounds__(64) void head_kernel(
    const float* __restrict__ x, const float* __restrict__ g,
    const float* __restrict__ b, const float* __restrict__ w,
    const float* __restrict__ ob, float* __restrict__ out)
{
    __shared__ float xn[DM];
    int lane = threadIdx.x;
    const float4* xr = (const float4*)x;
    float4 v0 = xr[lane * 2], v1 = xr[lane * 2 + 1];
    float s  = v0.x + v0.y + v0.z + v0.w + v1.x + v1.y + v1.z + v1.w;
    float s2 = v0.x*v0.x + v0.y*v0.y + v0.z*v0.z + v0.w*v0.w
             + v1.x*v1.x + v1.y*v1.y + v1.z*v1.z + v1.w*v1.w;
    #pragma unroll
    for (int off = 32; off >= 1; off >>= 1) {
        s  += __shfl_xor(s, off);
        s2 += __shfl_xor(s2, off);
    }
    float mu = s * (1.f / DM);
    float var = s2 * (1.f / DM) - mu * mu;
    float r = rsqrtf(var + LN_EPS);
    #pragma unroll
    for (int i = 0; i < 8; i++) {
        int d = lane * 8 + i;
        xn[d] = (x[d] - mu) * r * g[d] + b[d];
    }
    __syncthreads();
    if (lane < 60) {
        float a = ob[lane];
        for (int d = 0; d < DM; d++) a += xn[d] * w[d * 60 + lane];
        out[lane] = a;
    }
}

// ------------------------------ driver -------------------------------------
extern "C" void kernel_launch(void* const* d_in, const int* in_sizes, int n_in,
                              void* d_out, int out_size, void* d_ws, size_t ws_size,
                              hipStream_t stream)
{
    const float* video     = (const float*)d_in[0];
    const float* patch_w   = (const float*)d_in[1];
    const float* patch_b   = (const float*)d_in[2];
    const float* pos_emb   = (const float*)d_in[3];
    const float* cls_token = (const float*)d_in[4];
    const float* t_ln_g    = (const float*)d_in[5];
    const float* t_ln_b    = (const float*)d_in[6];
    const float* t_qkv_w   = (const float*)d_in[7];
    const float* t_out_w   = (const float*)d_in[8];
    const float* t_out_b   = (const float*)d_in[9];
    const float* s_ln_g    = (const float*)d_in[10];
    const float* s_ln_b    = (const float*)d_in[11];
    const float* s_qkv_w   = (const float*)d_in[12];
    const float* s_out_w   = (const float*)d_in[13];
    const float* s_out_b   = (const float*)d_in[14];
    const float* f_ln_g    = (const float*)d_in[15];
    const float* f_ln_b    = (const float*)d_in[16];
    const float* f_w1      = (const float*)d_in[17];
    const float* f_b1      = (const float*)d_in[18];
    const float* f_w2      = (const float*)d_in[19];
    const float* f_b2      = (const float*)d_in[20];
    const float* o_ln_g    = (const float*)d_in[21];
    const float* o_ln_b    = (const float*)d_in[22];
    const float* o_w       = (const float*)d_in[23];
    const float* o_b       = (const float*)d_in[24];

    char* ws = (char*)d_ws;
    size_t o = 0;
    float*          X    = (float*)(ws + o);          o += (size_t)(MP + 1) * 512 * 4;
    unsigned short* XN   = (unsigned short*)(ws + o); o += (size_t)MP * 512 * 2;
    unsigned short* QKV  = (unsigned short*)(ws + o); o += (size_t)MP * 1536 * 2;
    unsigned short* H16  = (unsigned short*)(ws + o); o += (size_t)MP * 4096 * 2;
    unsigned short* MID  = (unsigned short*)(ws + o); o += (size_t)MP * 2048 * 2;
    unsigned short* PT   = (unsigned short*)(ws + o); o += (size_t)MP * 768 * 2;
    unsigned short* W16  = (unsigned short*)(ws + o); o += (size_t)5242880 * 2;
    unsigned short* PW16 = (unsigned short*)(ws + o); o += (size_t)512 * 768 * 2;
    float*          CP   = (float*)(ws + o);          o += (size_t)8 * NCH * 68 * 4;

    // ---- patch embed + cls + pos ----
    patchify_kernel<<<(NP * 768 + 255) / 256, 256, 0, stream>>>(video, PT);
    cls_init_kernel<<<2, 256, 0, stream>>>(cls_token, pos_emb, X);
    posx_init<<<NP * DM / 4 / 256, 256, 0, stream>>>(pos_emb, X);
    convertT_one<<<(768 / 32) * (512 / 32), 256, 0, stream>>>(patch_w, PW16, 768, 512);
    mfma_gemm_sk<3><<<dim3(4, 38, 3), 256, 0, stream>>>(PT, PW16, patch_b,
                                                        X + DM, NP, DM, 768);

    dim3 g_qkv(12, 38), g_ff1(16, 38);
    dim3 g_out_sk(4, 38, 2), g_ff2_sk(4, 38, 4);
    for (int i = 0; i < 12; i++) {
        convertT_layer<<<5120, 256, 0, stream>>>(
            t_qkv_w + (size_t)i * 512 * 1536, t_out_w + (size_t)i * 512 * 512,
            s_qkv_w + (size_t)i * 512 * 1536, s_out_w + (size_t)i * 512 * 512,
            f_w1 + (size_t)i * 512 * 4096, f_w2 + (size_t)i * 2048 * 512, W16);

        // ---- time attention block ----
        ln_bf16<<<1201, 256, 0, stream>>>(X, t_ln_g + i * DM, t_ln_b + i * DM, XN, NT);
        mfma_gemm<true><<<g_qkv, 256, 0, stream>>>(XN, W16 + 0, nullptr, nullptr,
                                                   QKV, NT, QKV_ST, DM);
        time_attn4<<<600, 256, 0, stream>>>(QKV, MID);
        cls_attn_part<<<dim3(NCH, 8), 256, 0, stream>>>(QKV, CP);
        cls_attn_reduce<<<8, 64, 0, stream>>>(CP, MID);
        mfma_gemm_sk<2><<<g_out_sk, 256, 0, stream>>>(MID, W16 + 786432, t_out_b + i * DM,
                                                      X, NT, DM, DM);
        // ---- space attention block ----
        ln_bf16<<<1201, 256, 0, stream>>>(X, s_ln_g + i * DM, s_ln_b + i * DM, XN, NT);
        mfma_gemm<true><<<g_qkv, 256, 0, stream>>>(XN, W16 + 1048576, nullptr, nullptr,
                                                   QKV, NT, QKV_ST, DM);
        space_attn_mfma<<<dim3(5, 8, 8), 256, 0, stream>>>(QKV, MID);
        cls_attn_part<<<dim3(NCH, 8), 256, 0, stream>>>(QKV, CP);
        cls_attn_reduce<<<8, 64, 0, stream>>>(CP, MID);
        mfma_gemm_sk<2><<<g_out_sk, 256, 0, stream>>>(MID, W16 + 1835008, s_out_b + i * DM,
                                                      X, NT, DM, DM);
        // ---- GeGLU FF block (FF1 fused with GeGLU -> MID) ----
        ln_bf16<<<1201, 256, 0, stream>>>(X, f_ln_g + i * DM, f_ln_b + i * DM, XN, NT);
        mfma_ff1_geglu<<<g_ff1, 256, 0, stream>>>(XN, W16 + 2097152, f_b1 + i * 4096,
                                                  MID, NT);
        mfma_gemm_sk<4><<<g_ff2_sk, 256, 0, stream>>>(MID, W16 + 4194304, f_b2 + i * DM,
                                                      X, NT, DM, 2048);
    }

    head_kernel<<<1, 64, 0, stream>>>(X, o_ln_g, o_ln_b, o_w, o_b, (float*)d_out);
}